// Round 5
// baseline (1487.531 us; speedup 1.0000x reference)
//
#include <hip/hip_runtime.h>

#define N_NODES 100000
#define N_EDGES 800000
#define N_GRAPH 256
#define MP      100096   // 391 * 256, padded M
#define NH      512

typedef __bf16 bf16x4v __attribute__((ext_vector_type(4)));
typedef __bf16 bf16x8v __attribute__((ext_vector_type(8)));
typedef float  f32x4   __attribute__((ext_vector_type(4)));

__device__ __forceinline__ void gload_lds16(const void* g, void* l) {
  __builtin_amdgcn_global_load_lds((const __attribute__((address_space(1))) void*)g,
                                   (__attribute__((address_space(3))) void*)l, 16, 0, 0);
}

// order-preserving fp32 <-> uint32 encoding for atomicMax
__device__ __forceinline__ unsigned enc_f32(float f) {
  unsigned u = __float_as_uint(f);
  return (u & 0x80000000u) ? ~u : (u | 0x80000000u);
}
__device__ __forceinline__ float dec_f32(unsigned u) {
  return (u & 0x80000000u) ? __uint_as_float(u & 0x7FFFFFFFu) : __uint_as_float(~u);
}

// ---------------- cast x (fp32) -> padded bf16 [MP][512] ----------------
__global__ __launch_bounds__(256) void castx_kernel(const float* __restrict__ x,
                                                    __bf16* __restrict__ xb) {
  const size_t i = (size_t)blockIdx.x * 256 + threadIdx.x;   // 8-elem chunk id
  const size_t row = i >> 6;
  const int c = (int)(i & 63) * 8;
  if (row >= MP) return;
  bf16x8v o;
  if (row < N_NODES) {
    const float* p = x + row * 512 + c;
    f32x4 a = *(const f32x4*)p;
    f32x4 b = *(const f32x4*)(p + 4);
    o[0]=(__bf16)a[0]; o[1]=(__bf16)a[1]; o[2]=(__bf16)a[2]; o[3]=(__bf16)a[3];
    o[4]=(__bf16)b[0]; o[5]=(__bf16)b[1]; o[6]=(__bf16)b[2]; o[7]=(__bf16)b[3];
  } else {
    for (int j = 0; j < 8; ++j) o[j] = (__bf16)0.0f;
  }
  *(bf16x8v*)(xb + row * 512 + c) = o;
}

// ---------------- weight transpose: W[K][N] fp32 -> BT[N][K] bf16 ----------------
__global__ __launch_bounds__(256) void transpose_kernel(const float* __restrict__ W,
                                                        __bf16* __restrict__ BT,
                                                        int K, int Nn) {
  __shared__ float tile[32][33];
  const int bx = blockIdx.x;   // n tile
  const int by = blockIdx.y;   // k tile
  const int tx = threadIdx.x & 31;
  const int ty = threadIdx.x >> 5;   // 0..7
  for (int j = 0; j < 4; ++j) {
    int k = by * 32 + ty + j * 8;
    int n = bx * 32 + tx;
    tile[ty + j * 8][tx] = W[(size_t)k * Nn + n];
  }
  __syncthreads();
  for (int j = 0; j < 4; ++j) {
    int n = bx * 32 + ty + j * 8;
    int k = by * 32 + tx;
    BT[(size_t)n * K + k] = (__bf16)tile[tx][ty + j * 8];
  }
}

// ---------------- CSR build ----------------
__global__ __launch_bounds__(256) void degree_kernel(const int* __restrict__ dst,
                                                     int* __restrict__ deg) {
  int e = blockIdx.x * 256 + threadIdx.x;
  if (e < N_EDGES) atomicAdd(&deg[dst[e]], 1);
}

__global__ __launch_bounds__(256) void scan1_kernel(const int* __restrict__ deg,
                                                    int* __restrict__ rs,
                                                    int* __restrict__ bsum, int n) {
  __shared__ int lds[256];
  const int b = blockIdx.x, t = threadIdx.x;
  const int base = b * 1024 + t * 4;
  int v[4];
  for (int j = 0; j < 4; ++j) v[j] = (base + j < n) ? deg[base + j] : 0;
  int tsum = v[0] + v[1] + v[2] + v[3];
  lds[t] = tsum;
  __syncthreads();
  for (int off = 1; off < 256; off <<= 1) {
    int x = 0;
    if (t >= off) x = lds[t - off];
    __syncthreads();
    lds[t] += x;
    __syncthreads();
  }
  int run = lds[t] - tsum;   // exclusive prefix of this thread
  for (int j = 0; j < 4; ++j) {
    if (base + j < n) rs[base + j] = run;
    run += v[j];
  }
  if (t == 255) bsum[b] = lds[255];
}

__global__ void scan2_kernel(int* bsum, int nb) {
  if (threadIdx.x == 0 && blockIdx.x == 0) {
    int run = 0;
    for (int i = 0; i < nb; ++i) { int v = bsum[i]; bsum[i] = run; run += v; }
  }
}

__global__ __launch_bounds__(256) void scan3_kernel(int* __restrict__ rs,
                                                    const int* __restrict__ bsum,
                                                    int* __restrict__ cursor, int n) {
  int i = blockIdx.x * 256 + threadIdx.x;
  if (i < n) {
    int v = rs[i] + bsum[i >> 10];
    rs[i] = v;
    cursor[i] = v;
  } else if (i == n) {
    rs[n] = N_EDGES;
  }
}

__global__ __launch_bounds__(256) void scatter_kernel(const int* __restrict__ src,
                                                      const int* __restrict__ dst,
                                                      int* __restrict__ cursor,
                                                      int* __restrict__ csr) {
  int e = blockIdx.x * 256 + threadIdx.x;
  if (e < N_EDGES) {
    int slot = atomicAdd(&cursor[dst[e]], 1);
    csr[slot] = src[e];
  }
}

// ---------------- aggregate: agg[n] = sum_{e: dst==n} h[src[e]]  (pull, CSR) ----------------
__global__ __launch_bounds__(256) void aggregate_kernel(const __bf16* __restrict__ h,
                                                        const int* __restrict__ rs,
                                                        const int* __restrict__ csr,
                                                        __bf16* __restrict__ agg) {
  const int node = blockIdx.x * 4 + (threadIdx.x >> 6);
  if (node >= N_NODES) return;
  const int lane = threadIdx.x & 63;
  const int s = rs[node], e = rs[node + 1];
  float acc[8] = {0.f,0.f,0.f,0.f,0.f,0.f,0.f,0.f};
  for (int i = s; i < e; ++i) {
    int sn = csr[i];
    bf16x8v v = *(const bf16x8v*)(h + (size_t)sn * 512 + lane * 8);
    for (int j = 0; j < 8; ++j) acc[j] += (float)v[j];
  }
  bf16x8v o;
  for (int j = 0; j < 8; ++j) o[j] = (__bf16)acc[j];
  *(bf16x8v*)(agg + (size_t)node * 512 + lane * 8) = o;
}

// ---------------- GEMM 256x256, BK=32: A via LDS ring-4, B via registers ---------------
// C[M][512] = relu?( A @ BT^T + bias ), bf16 in/out, fp32 acc.
// 512 threads = 8 waves (2M x 4N), wave output 128x64.
// A: LDS ring of 4 slots (16KB each, 64KB total), staged 3 tiles ahead (gload_lds).
// B: per-wave fragments loaded global->VGPR (L2-hot weight slab), double-buffered one
//    K-tile ahead in named register sets (unroll-by-2, no dynamic indexing).
// vmcnt discipline: per tile issues [4 bv loads][2 A stages]; vmcnt(2) at tile top
// drains bv(tk)+A(tk) while keeping A(tk+2)'s stages in flight; vmcnt(0) last 3 tiles.
// Chunk swizzle on A (involution, inverse-swizzled source + swizzled read): proven 0-conflict.
template<int KTOT, bool SPLIT, bool RELU>
__global__ __launch_bounds__(512, 2) void gemm256_kernel(const __bf16* __restrict__ A1,
                                                         const __bf16* __restrict__ A2,
                                                         const __bf16* __restrict__ BT,
                                                         const float* __restrict__ bias,
                                                         __bf16* __restrict__ C) {
  extern __shared__ char smem[];
  __bf16* As = (__bf16*)smem;              // 4 slots * 256*32 elems = 64KB
  const int tid  = threadIdx.x;
  const int wid  = tid >> 6;     // 0..7
  const int lane = tid & 63;
  const int wm = wid >> 2;       // 0..1
  const int wn = wid & 3;        // 0..3
  const int srow = tid >> 2;     // 0..127 (row within 128-row half)
  const int scol = ((tid & 3) ^ ((tid >> 3) & 3)) * 8;   // inverse-swizzled source chunk
  const int rl  = lane & 15;
  const int rdk = (((lane >> 4) ^ ((lane >> 1) & 3)) * 8);  // swizzled read chunk
  const int k8  = (lane >> 4) * 8;                           // linear k chunk (B from global)

  // XCD-aware bijective remap (782 = 6*98 + 2*97); pairs (tn=0,1) of a tm share an XCD
  const int bid = blockIdx.x;
  const int xcd = bid & 7, pos = bid >> 3;
  const int idx = (xcd < 6) ? (xcd * 98 + pos) : (588 + (xcd - 6) * 97 + pos);
  const int tm = idx >> 1, tn = idx & 1;

  constexpr int NT = KTOT / 32;

  f32x4 acc[8][4];
#pragma unroll
  for (int mi = 0; mi < 8; ++mi)
#pragma unroll
    for (int ni = 0; ni < 4; ++ni)
      acc[mi][ni] = f32x4{0.f, 0.f, 0.f, 0.f};

  auto stage = [&](int tk) {
    const int slot = tk & 3;
    const __bf16* Ap = A1;
    int kc = tk * 32;
    if (SPLIT && tk >= NT / 2) { Ap = A2; kc = (tk - NT / 2) * 32; }
#pragma unroll
    for (int j = 0; j < 2; ++j) {
      const __bf16* g = Ap + (size_t)(tm * 256 + j * 128 + srow) * NH + (kc + scol);
      gload_lds16(g, (char*)As + slot * 16384 + j * 8192 + wid * 1024);
    }
  };

  const __bf16* Bbase = BT + (size_t)(tn * 256 + wn * 64 + rl) * KTOT + k8;
  auto loadB = [&](int tk, bf16x8v* bv) {
#pragma unroll
    for (int ni = 0; ni < 4; ++ni)
      bv[ni] = *(const bf16x8v*)(Bbase + tk * 32 + (size_t)ni * 16 * KTOT);
  };

  auto compute = [&](int slot, const bf16x8v* bv) {
    const __bf16* a0 = As + slot * 8192 + (wm * 128 + rl) * 32 + rdk;
#pragma unroll
    for (int h = 0; h < 2; ++h) {
      bf16x8v av[4];
#pragma unroll
      for (int mi = 0; mi < 4; ++mi)
        av[mi] = *(const bf16x8v*)(a0 + (h * 64 + mi * 16) * 32);
      __builtin_amdgcn_s_setprio(1);
#pragma unroll
      for (int mi = 0; mi < 4; ++mi)
#pragma unroll
        for (int ni = 0; ni < 4; ++ni)
          acc[h * 4 + mi][ni] =
              __builtin_amdgcn_mfma_f32_16x16x32_bf16(av[mi], bv[ni], acc[h * 4 + mi][ni], 0, 0, 0);
      __builtin_amdgcn_s_setprio(0);
    }
  };

  auto waitv = [&](int tk) {
    if (tk <= NT - 4) asm volatile("s_waitcnt vmcnt(2)" ::: "memory");
    else              asm volatile("s_waitcnt vmcnt(0)" ::: "memory");
  };

  bf16x8v bvA[4], bvB[4];
  // prologue: bv(0) first, then A stages for tiles 0..2 (order matters for vmcnt math)
  loadB(0, bvA);
  stage(0); stage(1); stage(2);

  for (int it = 0; it < NT / 2; ++it) {
    const int t0 = 2 * it, t1 = 2 * it + 1;
    // ---- even tile: consume bvA ----
    waitv(t0);
    __builtin_amdgcn_s_barrier();
    asm volatile("" ::: "memory");
    loadB(t1, bvB);                       // prefetch next tile's B into regs
    if (t0 + 3 < NT) stage(t0 + 3);       // overwrites slot (t0-1)&3 -- safe post-barrier
    compute(t0 & 3, bvA);
    // ---- odd tile: consume bvB ----
    waitv(t1);
    __builtin_amdgcn_s_barrier();
    asm volatile("" ::: "memory");
    if (t1 + 1 < NT) loadB(t1 + 1, bvA);
    if (t1 + 3 < NT) stage(t1 + 3);
    compute(t1 & 3, bvB);
  }

  // epilogue: bias (+ relu) -> bf16
  const int rg = (lane >> 4) * 4;
#pragma unroll
  for (int ni = 0; ni < 4; ++ni) {
    const int col = tn * 256 + wn * 64 + ni * 16 + rl;
    const float bv_ = bias[col];
#pragma unroll
    for (int mi = 0; mi < 8; ++mi) {
      const int rowb = tm * 256 + wm * 128 + mi * 16 + rg;
#pragma unroll
      for (int r = 0; r < 4; ++r) {
        float v = acc[mi][ni][r] + bv_;
        if (RELU) v = fmaxf(v, 0.f);
        C[(size_t)(rowb + r) * NH + col] = (__bf16)v;
      }
    }
  }
}

// ---------------- memory module: h = softmax(h @ mem^T) @ mem ; also write hc slice --------
__global__ __launch_bounds__(256) void memmod_kernel(__bf16* __restrict__ h,
                                                     const float* __restrict__ mem,
                                                     __bf16* __restrict__ hc, int colofs) {
  __shared__ float sm[8 * 512];
  const int tid = threadIdx.x;
  for (int i = tid; i < 4096; i += 256) sm[i] = mem[i];
  __syncthreads();
  const int node = blockIdx.x * 4 + (tid >> 6);
  if (node >= N_NODES) return;
  const int lane = tid & 63;
  __bf16* hrow = h + (size_t)node * 512;
  float hv[8];
  for (int j = 0; j < 8; ++j) hv[j] = (float)hrow[lane + j * 64];
  float sim[8];
  for (int m = 0; m < 8; ++m) {
    float p = 0.f;
    const float* mr = sm + m * 512 + lane;
    for (int j = 0; j < 8; ++j) p += hv[j] * mr[j * 64];
    for (int off = 32; off; off >>= 1) p += __shfl_xor(p, off, 64);
    sim[m] = p;
  }
  float mx = sim[0];
  for (int m = 1; m < 8; ++m) mx = fmaxf(mx, sim[m]);
  float s = 0.f;
  for (int m = 0; m < 8; ++m) { sim[m] = __expf(sim[m] - mx); s += sim[m]; }
  const float inv = 1.f / s;
  float outv[8] = {0.f,0.f,0.f,0.f,0.f,0.f,0.f,0.f};
  for (int m = 0; m < 8; ++m) {
    float w = sim[m] * inv;
    const float* mr = sm + m * 512 + lane;
    for (int j = 0; j < 8; ++j) outv[j] += w * mr[j * 64];
  }
  __bf16* hcrow = hc + (size_t)node * 1024 + colofs;
  for (int j = 0; j < 8; ++j) {
    __bf16 o = (__bf16)outv[j];
    hrow[lane + j * 64] = o;
    hcrow[lane + j * 64] = o;
  }
}

// ---------------- graph ranges (batch is sorted) ----------------
__global__ __launch_bounds__(256) void ranges_kernel(const int* __restrict__ batch,
                                                     int* __restrict__ gstart) {
  int g = blockIdx.x * 256 + threadIdx.x;
  if (g > N_GRAPH) return;
  if (g == N_GRAPH) { gstart[N_GRAPH] = N_NODES; return; }
  int lo = 0, hi = N_NODES;
  while (lo < hi) {
    int mid = (lo + hi) >> 1;
    if (batch[mid] < g) lo = mid + 1; else hi = mid;
  }
  gstart[g] = lo;
}

// ---------------- pooling phase 1: segmented max/sum over hc [N][1024] ----------------
__global__ __launch_bounds__(256) void pool1_kernel(const __bf16* __restrict__ hc,
                                                    const int* __restrict__ batch,
                                                    unsigned* __restrict__ gmax,
                                                    float* __restrict__ gsum) {
  __shared__ int bsh[128];
  const int r0 = blockIdx.x * 128;
  const int t = threadIdx.x;
  const int nrows = min(128, N_NODES - r0);
  if (t < nrows) bsh[t] = batch[r0 + t];
  __syncthreads();
  float mx[4] = {-3.0e38f, -3.0e38f, -3.0e38f, -3.0e38f};
  float sm[4] = {0.f, 0.f, 0.f, 0.f};
  int cur = -1;
  for (int r = 0; r < nrows; ++r) {
    int g = bsh[r];
    if (g != cur) {
      if (cur >= 0) {
#pragma unroll
        for (int j = 0; j < 4; ++j) {
          atomicMax(&gmax[(size_t)cur * 1024 + t * 4 + j], enc_f32(mx[j]));
          atomicAdd(&gsum[(size_t)cur * 1024 + t * 4 + j], sm[j]);
        }
      }
      cur = g;
#pragma unroll
      for (int j = 0; j < 4; ++j) { mx[j] = -3.0e38f; sm[j] = 0.f; }
    }
    bf16x4v v = *(const bf16x4v*)(hc + (size_t)(r0 + r) * 1024 + t * 4);
#pragma unroll
    for (int j = 0; j < 4; ++j) {
      float f = (float)v[j];
      mx[j] = fmaxf(mx[j], f);
      sm[j] += f;
    }
  }
  if (cur >= 0) {
#pragma unroll
    for (int j = 0; j < 4; ++j) {
      atomicMax(&gmax[(size_t)cur * 1024 + t * 4 + j], enc_f32(mx[j]));
      atomicAdd(&gsum[(size_t)cur * 1024 + t * 4 + j], sm[j]);
    }
  }
}

// ---------------- pooling phase 2: decode to gf [G][2048] = [max | mean] ----------------
__global__ __launch_bounds__(256) void pool2_kernel(const unsigned* __restrict__ gmax,
                                                    const float* __restrict__ gsum,
                                                    const int* __restrict__ gstart,
                                                    float* __restrict__ g) {
  const int gr = blockIdx.x;
  const int t = threadIdx.x;
  const int cnt = gstart[gr + 1] - gstart[gr];
  const float inv = 1.f / fmaxf((float)cnt, 1.f);
#pragma unroll
  for (int j = 0; j < 4; ++j) {
    const int f = t * 4 + j;
    unsigned u = gmax[(size_t)gr * 1024 + f];
    g[(size_t)gr * 2048 + f] = (cnt > 0) ? dec_f32(u) : 0.f;
    g[(size_t)gr * 2048 + 1024 + f] = gsum[(size_t)gr * 1024 + f] * inv;
  }
}

// ---------------- classifier head: log_softmax(g @ lin_w + lin_b) ----------------
__global__ __launch_bounds__(64) void classify_kernel(const float* __restrict__ g,
                                                      const float* __restrict__ lw,
                                                      const float* __restrict__ lb,
                                                      float* __restrict__ out) {
  const int gr = blockIdx.x;
  const int lane = threadIdx.x;   // 64
  float acc[10];
  for (int c = 0; c < 10; ++c) acc[c] = 0.f;
  const float* grow = g + (size_t)gr * 2048;
  for (int k = lane; k < 2048; k += 64) {
    float gv = grow[k];
    const float* w = lw + (size_t)k * 10;
#pragma unroll
    for (int c = 0; c < 10; ++c) acc[c] += gv * w[c];
  }
  for (int c = 0; c < 10; ++c)
    for (int off = 32; off; off >>= 1) acc[c] += __shfl_xor(acc[c], off, 64);
  if (lane == 0) {
    float lg[10];
    float mx = -3.0e38f;
    for (int c = 0; c < 10; ++c) { lg[c] = acc[c] + lb[c]; mx = fmaxf(mx, lg[c]); }
    float s = 0.f;
    for (int c = 0; c < 10; ++c) s += expf(lg[c] - mx);
    float lse = logf(s);
    for (int c = 0; c < 10; ++c) out[(size_t)gr * 10 + c] = lg[c] - mx - lse;
  }
}

// =======================================================================================
extern "C" void kernel_launch(void* const* d_in, const int* in_sizes, int n_in,
                              void* d_out, int out_size, void* d_ws, size_t ws_size,
                              hipStream_t stream) {
  (void)in_sizes; (void)n_in; (void)out_size; (void)ws_size;
  const float* x      = (const float*)d_in[0];
  const int*   eidx   = (const int*)d_in[1];
  const int*   batch  = (const int*)d_in[2];
  const float* pre_w  = (const float*)d_in[4];
  const float* pre_b  = (const float*)d_in[5];
  const float* w1_0   = (const float*)d_in[6];
  const float* b1_0   = (const float*)d_in[7];
  const float* w2_0   = (const float*)d_in[8];
  const float* b2_0   = (const float*)d_in[9];
  const float* mem_0  = (const float*)d_in[10];
  const float* w1_1   = (const float*)d_in[11];
  const float* b1_1   = (const float*)d_in[12];
  const float* w2_1   = (const float*)d_in[13];
  const float* b2_1   = (const float*)d_in[14];
  const float* mem_1  = (const float*)d_in[15];
  const float* lin_w  = (const float*)d_in[16];
  const float* lin_b  = (const float*)d_in[17];
  float* out = (float*)d_out;

  const int* src = eidx;
  const int* dst = eidx + N_EDGES;

  // ---- workspace carve ----
  char* p = (char*)d_ws;
  auto alloc = [&](size_t bytes) -> char* {
    char* r = p;
    p += (bytes + 255) & ~(size_t)255;
    return r;
  };
  __bf16* xb    = (__bf16*)alloc((size_t)MP * 512 * 2);
  __bf16* hb    = (__bf16*)alloc((size_t)MP * 512 * 2);
  __bf16* aggb  = (__bf16*)alloc((size_t)MP * 512 * 2);
  __bf16* y1b   = (__bf16*)alloc((size_t)MP * 512 * 2);
  __bf16* hcb   = (__bf16*)alloc((size_t)MP * 1024 * 2);
  __bf16* preT  = (__bf16*)alloc((size_t)512 * 512 * 2);
  __bf16* w1T0  = (__bf16*)alloc((size_t)512 * 1024 * 2);
  __bf16* w2T0  = (__bf16*)alloc((size_t)512 * 512 * 2);
  __bf16* w1T1  = (__bf16*)alloc((size_t)512 * 1024 * 2);
  __bf16* w2T1  = (__bf16*)alloc((size_t)512 * 512 * 2);
  int* deg      = (int*)alloc((size_t)N_NODES * 4);
  int* rowstart = (int*)alloc((size_t)(N_NODES + 1) * 4);
  int* cursor   = (int*)alloc((size_t)N_NODES * 4);
  int* bsum     = (int*)alloc(128 * 4);
  int* csr      = (int*)alloc((size_t)N_EDGES * 4);
  int* gstart   = (int*)alloc((size_t)(N_GRAPH + 1) * 4);
  float* gf     = (float*)alloc((size_t)N_GRAPH * 2048 * 4);
  unsigned* gmax = (unsigned*)alloc((size_t)N_GRAPH * 1024 * 4);
  float* gsum    = (float*)alloc((size_t)N_GRAPH * 1024 * 4);

  // ---- enable 64KB dynamic LDS for the GEMM instantiations (host-side, capture-safe) ----
  const int GEMM_LDS = 65536;
  hipFuncSetAttribute(reinterpret_cast<const void*>(&gemm256_kernel<512,  false, false>),
                      hipFuncAttributeMaxDynamicSharedMemorySize, GEMM_LDS);
  hipFuncSetAttribute(reinterpret_cast<const void*>(&gemm256_kernel<1024, true,  true>),
                      hipFuncAttributeMaxDynamicSharedMemorySize, GEMM_LDS);
  hipFuncSetAttribute(reinterpret_cast<const void*>(&gemm256_kernel<512,  false, true>),
                      hipFuncAttributeMaxDynamicSharedMemorySize, GEMM_LDS);

  // ---- weight prep (bf16 transposed: BT[n][k]) ----
  transpose_kernel<<<dim3(16, 16), 256, 0, stream>>>(pre_w, preT, 512, 512);
  transpose_kernel<<<dim3(16, 32), 256, 0, stream>>>(w1_0, w1T0, 1024, 512);
  transpose_kernel<<<dim3(16, 16), 256, 0, stream>>>(w2_0, w2T0, 512, 512);
  transpose_kernel<<<dim3(16, 32), 256, 0, stream>>>(w1_1, w1T1, 1024, 512);
  transpose_kernel<<<dim3(16, 16), 256, 0, stream>>>(w2_1, w2T1, 512, 512);

  // ---- input cast ----
  castx_kernel<<<25024, 256, 0, stream>>>(x, xb);

  // ---- CSR build (per call; deterministic work) ----
  hipMemsetAsync(deg, 0, (size_t)N_NODES * 4, stream);
  degree_kernel<<<3125, 256, 0, stream>>>(dst, deg);
  scan1_kernel<<<98, 256, 0, stream>>>(deg, rowstart, bsum, N_NODES);
  scan2_kernel<<<1, 64, 0, stream>>>(bsum, 98);
  scan3_kernel<<<392, 256, 0, stream>>>(rowstart, bsum, cursor, N_NODES);
  scatter_kernel<<<3125, 256, 0, stream>>>(src, dst, cursor, csr);

  // pooling accumulators: gmax||gsum are contiguous -> one memset
  hipMemsetAsync(gmax, 0, (size_t)N_GRAPH * 1024 * 4 * 2, stream);
  ranges_kernel<<<2, 256, 0, stream>>>(batch, gstart);

  const int GG = 782;   // 391 M-tiles x 2 N-tiles

  // ---- pre conv: h = x @ pre_w + pre_b ----
  gemm256_kernel<512, false, false><<<GG, 512, GEMM_LDS, stream>>>(xb, nullptr, preT, pre_b, hb);

  // ---- layer 0 ----
  aggregate_kernel<<<25000, 256, 0, stream>>>(hb, rowstart, csr, aggb);
  gemm256_kernel<1024, true, true><<<GG, 512, GEMM_LDS, stream>>>(hb, aggb, w1T0, b1_0, y1b);
  gemm256_kernel<512, false, true><<<GG, 512, GEMM_LDS, stream>>>(y1b, nullptr, w2T0, b2_0, hb);
  memmod_kernel<<<25000, 256, 0, stream>>>(hb, mem_0, hcb, 0);

  // ---- layer 1 ----
  aggregate_kernel<<<25000, 256, 0, stream>>>(hb, rowstart, csr, aggb);
  gemm256_kernel<1024, true, true><<<GG, 512, GEMM_LDS, stream>>>(hb, aggb, w1T1, b1_1, y1b);
  gemm256_kernel<512, false, true><<<GG, 512, GEMM_LDS, stream>>>(y1b, nullptr, w2T1, b2_1, hb);
  memmod_kernel<<<25000, 256, 0, stream>>>(hb, mem_1, hcb, 512);

  // ---- readout ----
  pool1_kernel<<<782, 256, 0, stream>>>(hcb, batch, gmax, gsum);
  pool2_kernel<<<N_GRAPH, 256, 0, stream>>>(gmax, gsum, gstart, gf);
  classify_kernel<<<N_GRAPH, 64, 0, stream>>>(gf, lin_w, lin_b, out);
}

// Round 6
// 1279.524 us; speedup vs baseline: 1.1626x; 1.1626x over previous
//
#include <hip/hip_runtime.h>

#define N_NODES 100000
#define N_EDGES 800000
#define N_GRAPH 256
#define MP      100096   // 391 * 256, padded M
#define NH      512

typedef __bf16 bf16x4v __attribute__((ext_vector_type(4)));
typedef __bf16 bf16x8v __attribute__((ext_vector_type(8)));
typedef float  f32x4   __attribute__((ext_vector_type(4)));

__device__ __forceinline__ void gload_lds16(const void* g, void* l) {
  __builtin_amdgcn_global_load_lds((const __attribute__((address_space(1))) void*)g,
                                   (__attribute__((address_space(3))) void*)l, 16, 0, 0);
}

// order-preserving fp32 <-> uint32 encoding for atomicMax
__device__ __forceinline__ unsigned enc_f32(float f) {
  unsigned u = __float_as_uint(f);
  return (u & 0x80000000u) ? ~u : (u | 0x80000000u);
}
__device__ __forceinline__ float dec_f32(unsigned u) {
  return (u & 0x80000000u) ? __uint_as_float(u & 0x7FFFFFFFu) : __uint_as_float(~u);
}

// ---------------- cast x (fp32) -> padded bf16 [MP][512] ----------------
__global__ __launch_bounds__(256) void castx_kernel(const float* __restrict__ x,
                                                    __bf16* __restrict__ xb) {
  const size_t i = (size_t)blockIdx.x * 256 + threadIdx.x;   // 8-elem chunk id
  const size_t row = i >> 6;
  const int c = (int)(i & 63) * 8;
  if (row >= MP) return;
  bf16x8v o;
  if (row < N_NODES) {
    const float* p = x + row * 512 + c;
    f32x4 a = *(const f32x4*)p;
    f32x4 b = *(const f32x4*)(p + 4);
    o[0]=(__bf16)a[0]; o[1]=(__bf16)a[1]; o[2]=(__bf16)a[2]; o[3]=(__bf16)a[3];
    o[4]=(__bf16)b[0]; o[5]=(__bf16)b[1]; o[6]=(__bf16)b[2]; o[7]=(__bf16)b[3];
  } else {
    for (int j = 0; j < 8; ++j) o[j] = (__bf16)0.0f;
  }
  *(bf16x8v*)(xb + row * 512 + c) = o;
}

// ---------------- weight transpose: W[K][N] fp32 -> BT[N][K] bf16 ----------------
__global__ __launch_bounds__(256) void transpose_kernel(const float* __restrict__ W,
                                                        __bf16* __restrict__ BT,
                                                        int K, int Nn) {
  __shared__ float tile[32][33];
  const int bx = blockIdx.x;   // n tile
  const int by = blockIdx.y;   // k tile
  const int tx = threadIdx.x & 31;
  const int ty = threadIdx.x >> 5;   // 0..7
  for (int j = 0; j < 4; ++j) {
    int k = by * 32 + ty + j * 8;
    int n = bx * 32 + tx;
    tile[ty + j * 8][tx] = W[(size_t)k * Nn + n];
  }
  __syncthreads();
  for (int j = 0; j < 4; ++j) {
    int n = bx * 32 + ty + j * 8;
    int k = by * 32 + tx;
    BT[(size_t)n * K + k] = (__bf16)tile[tx][ty + j * 8];
  }
}

// ---------------- CSR build ----------------
__global__ __launch_bounds__(256) void degree_kernel(const int* __restrict__ dst,
                                                     int* __restrict__ deg) {
  int e = blockIdx.x * 256 + threadIdx.x;
  if (e < N_EDGES) atomicAdd(&deg[dst[e]], 1);
}

__global__ __launch_bounds__(256) void scan1_kernel(const int* __restrict__ deg,
                                                    int* __restrict__ rs,
                                                    int* __restrict__ bsum, int n) {
  __shared__ int lds[256];
  const int b = blockIdx.x, t = threadIdx.x;
  const int base = b * 1024 + t * 4;
  int v[4];
  for (int j = 0; j < 4; ++j) v[j] = (base + j < n) ? deg[base + j] : 0;
  int tsum = v[0] + v[1] + v[2] + v[3];
  lds[t] = tsum;
  __syncthreads();
  for (int off = 1; off < 256; off <<= 1) {
    int x = 0;
    if (t >= off) x = lds[t - off];
    __syncthreads();
    lds[t] += x;
    __syncthreads();
  }
  int run = lds[t] - tsum;   // exclusive prefix of this thread
  for (int j = 0; j < 4; ++j) {
    if (base + j < n) rs[base + j] = run;
    run += v[j];
  }
  if (t == 255) bsum[b] = lds[255];
}

__global__ void scan2_kernel(int* bsum, int nb) {
  if (threadIdx.x == 0 && blockIdx.x == 0) {
    int run = 0;
    for (int i = 0; i < nb; ++i) { int v = bsum[i]; bsum[i] = run; run += v; }
  }
}

__global__ __launch_bounds__(256) void scan3_kernel(int* __restrict__ rs,
                                                    const int* __restrict__ bsum,
                                                    int* __restrict__ cursor, int n) {
  int i = blockIdx.x * 256 + threadIdx.x;
  if (i < n) {
    int v = rs[i] + bsum[i >> 10];
    rs[i] = v;
    cursor[i] = v;
  } else if (i == n) {
    rs[n] = N_EDGES;
  }
}

__global__ __launch_bounds__(256) void scatter_kernel(const int* __restrict__ src,
                                                      const int* __restrict__ dst,
                                                      int* __restrict__ cursor,
                                                      int* __restrict__ csr) {
  int e = blockIdx.x * 256 + threadIdx.x;
  if (e < N_EDGES) {
    int slot = atomicAdd(&cursor[dst[e]], 1);
    csr[slot] = src[e];
  }
}

// ---------------- aggregate: agg[n] = sum_{e: dst==n} h[src[e]]  (pull, CSR) ----------------
__global__ __launch_bounds__(256) void aggregate_kernel(const __bf16* __restrict__ h,
                                                        const int* __restrict__ rs,
                                                        const int* __restrict__ csr,
                                                        __bf16* __restrict__ agg) {
  const int node = blockIdx.x * 4 + (threadIdx.x >> 6);
  if (node >= N_NODES) return;
  const int lane = threadIdx.x & 63;
  const int s = rs[node], e = rs[node + 1];
  float acc[8] = {0.f,0.f,0.f,0.f,0.f,0.f,0.f,0.f};
  for (int i = s; i < e; ++i) {
    int sn = csr[i];
    bf16x8v v = *(const bf16x8v*)(h + (size_t)sn * 512 + lane * 8);
    for (int j = 0; j < 8; ++j) acc[j] += (float)v[j];
  }
  bf16x8v o;
  for (int j = 0; j < 8; ++j) o[j] = (__bf16)acc[j];
  *(bf16x8v*)(agg + (size_t)node * 512 + lane * 8) = o;
}

// ---------------- GEMM 256x256, BK=32, ring-4 LDS + 2-phase interleave ----------------
// C[M][512] = relu?( A @ BT^T + bias ), bf16 in/out, fp32 acc.
// 512 threads = 8 waves (2M x 4N), wave output 128x64.
// A,B: LDS rings of 4 slots (16KB each tensor-slot; 128KB total), staged 3 tiles ahead.
// Per K-tile, TWO phases (m-halves): {ds_read subtile; stage one half; barrier;
// setprio+16 MFMA; barrier}. Counted vmcnt(8) after phase-1's MFMA, before its closing
// barrier (drain = tile t+1's 4 loads, certified block-wide by the barrier). Never 0
// until the tail. Chunk swizzle (inverse-swizzled source + swizzled read): measured
// 0-conflict in rounds 3-4.
template<int KTOT, bool SPLIT, bool RELU>
__global__ __launch_bounds__(512, 2) void gemm8p_kernel(const __bf16* __restrict__ A1,
                                                        const __bf16* __restrict__ A2,
                                                        const __bf16* __restrict__ BT,
                                                        const float* __restrict__ bias,
                                                        __bf16* __restrict__ C) {
  extern __shared__ char smem[];
  __bf16* As = (__bf16*)smem;              // 4 slots * 16KB = 64KB
  __bf16* Bs = (__bf16*)(smem + 65536);    // 64KB
  constexpr int NT = KTOT / 32;
  const int tid  = threadIdx.x;
  const int wid  = tid >> 6;     // 0..7
  const int lane = tid & 63;
  const int wm = wid >> 2;       // 0..1
  const int wn = wid & 3;        // 0..3
  const int srow = tid >> 2;     // 0..127
  const int scol = ((tid & 3) ^ ((tid >> 3) & 3)) * 8;      // inverse-swizzled source chunk
  const int rl  = lane & 15;
  const int rdk = (((lane >> 4) ^ ((lane >> 1) & 3)) * 8);  // swizzled read chunk

  // XCD-aware bijective remap (782 = 6*98 + 2*97); both N-tiles of a tm share an XCD
  const int bid = blockIdx.x;
  const int xcd = bid & 7, pos = bid >> 3;
  const int idx = (xcd < 6) ? (xcd * 98 + pos) : (588 + (xcd - 6) * 97 + pos);
  const int tm = idx >> 1, tn = idx & 1;

  f32x4 acc[8][4];
#pragma unroll
  for (int mi = 0; mi < 8; ++mi)
#pragma unroll
    for (int ni = 0; ni < 4; ++ni)
      acc[mi][ni] = f32x4{0.f, 0.f, 0.f, 0.f};

  auto stageA = [&](int tk) {
    const int slot = tk & 3;
    const __bf16* Ap = A1;
    int kc = tk * 32;
    if (SPLIT && tk >= NT / 2) { Ap = A2; kc = (tk - NT / 2) * 32; }
#pragma unroll
    for (int j = 0; j < 2; ++j) {
      const __bf16* g = Ap + (size_t)(tm * 256 + j * 128 + srow) * NH + (kc + scol);
      gload_lds16(g, (char*)As + slot * 16384 + j * 8192 + wid * 1024);
    }
  };
  auto stageB = [&](int tk) {
    const int slot = tk & 3;
#pragma unroll
    for (int j = 0; j < 2; ++j) {
      const __bf16* g = BT + (size_t)(tn * 256 + j * 128 + srow) * KTOT + (tk * 32 + scol);
      gload_lds16(g, (char*)Bs + slot * 16384 + j * 8192 + wid * 1024);
    }
  };

  // prologue: tiles 0..2 staged (12 loads); drain tile 0 (oldest 4), certify via barrier
  stageA(0); stageB(0); stageA(1); stageB(1); stageA(2); stageB(2);
  asm volatile("s_waitcnt vmcnt(8)" ::: "memory");
  __builtin_amdgcn_s_barrier();
  asm volatile("" ::: "memory");

  for (int t = 0; t < NT; ++t) {
    const int slot = t & 3;
    const __bf16* a0 = As + slot * 8192 + (wm * 128 + rl) * 32 + rdk;
    const __bf16* b0 = Bs + slot * 8192 + (wn * 64 + rl) * 32 + rdk;

    bf16x8v bv[4], av[4];
    // ---- phase 0: m-half 0 ----
#pragma unroll
    for (int ni = 0; ni < 4; ++ni) bv[ni] = *(const bf16x8v*)(b0 + ni * 16 * 32);
#pragma unroll
    for (int mi = 0; mi < 4; ++mi) av[mi] = *(const bf16x8v*)(a0 + mi * 16 * 32);
    if (t + 3 < NT) stageA(t + 3);
    asm volatile("" ::: "memory");
    __builtin_amdgcn_s_barrier();
    asm volatile("" ::: "memory");
    __builtin_amdgcn_s_setprio(1);
#pragma unroll
    for (int mi = 0; mi < 4; ++mi)
#pragma unroll
      for (int ni = 0; ni < 4; ++ni)
        acc[mi][ni] = __builtin_amdgcn_mfma_f32_16x16x32_bf16(av[mi], bv[ni], acc[mi][ni], 0, 0, 0);
    __builtin_amdgcn_s_setprio(0);
    asm volatile("" ::: "memory");
    __builtin_amdgcn_s_barrier();
    asm volatile("" ::: "memory");

    // ---- phase 1: m-half 1 (bv reused) ----
#pragma unroll
    for (int mi = 0; mi < 4; ++mi) av[mi] = *(const bf16x8v*)(a0 + (64 + mi * 16) * 32);
    if (t + 3 < NT) stageB(t + 3);
    asm volatile("" ::: "memory");
    __builtin_amdgcn_s_barrier();
    asm volatile("" ::: "memory");
    __builtin_amdgcn_s_setprio(1);
#pragma unroll
    for (int mi = 0; mi < 4; ++mi)
#pragma unroll
      for (int ni = 0; ni < 4; ++ni)
        acc[4 + mi][ni] = __builtin_amdgcn_mfma_f32_16x16x32_bf16(av[mi], bv[ni], acc[4 + mi][ni], 0, 0, 0);
    __builtin_amdgcn_s_setprio(0);
    // counted drain of tile t+1's 4 loads, hidden behind the MFMA cluster above;
    // the closing barrier certifies the drain block-wide before t+1's reads.
    if (t <= NT - 4)      { asm volatile("s_waitcnt vmcnt(8)" ::: "memory"); }
    else if (t == NT - 3) { asm volatile("s_waitcnt vmcnt(4)" ::: "memory"); }
    else if (t == NT - 2) { asm volatile("s_waitcnt vmcnt(0)" ::: "memory"); }
    __builtin_amdgcn_s_barrier();
    asm volatile("" ::: "memory");
  }

  // epilogue: bias (+ relu) -> bf16
  const int rg = (lane >> 4) * 4;
#pragma unroll
  for (int ni = 0; ni < 4; ++ni) {
    const int col = tn * 256 + wn * 64 + ni * 16 + rl;
    const float bv_ = bias[col];
#pragma unroll
    for (int mi = 0; mi < 8; ++mi) {
      const int rowb = tm * 256 + wm * 128 + mi * 16 + rg;
#pragma unroll
      for (int r = 0; r < 4; ++r) {
        float v = acc[mi][ni][r] + bv_;
        if (RELU) v = fmaxf(v, 0.f);
        C[(size_t)(rowb + r) * NH + col] = (__bf16)v;
      }
    }
  }
}

// ---------------- memory module: h = softmax(h @ mem^T) @ mem ; also write hc slice --------
__global__ __launch_bounds__(256) void memmod_kernel(__bf16* __restrict__ h,
                                                     const float* __restrict__ mem,
                                                     __bf16* __restrict__ hc, int colofs) {
  __shared__ float sm[8 * 512];
  const int tid = threadIdx.x;
  for (int i = tid; i < 4096; i += 256) sm[i] = mem[i];
  __syncthreads();
  const int node = blockIdx.x * 4 + (tid >> 6);
  if (node >= N_NODES) return;
  const int lane = tid & 63;
  __bf16* hrow = h + (size_t)node * 512;
  float hv[8];
  for (int j = 0; j < 8; ++j) hv[j] = (float)hrow[lane + j * 64];
  float sim[8];
  for (int m = 0; m < 8; ++m) {
    float p = 0.f;
    const float* mr = sm + m * 512 + lane;
    for (int j = 0; j < 8; ++j) p += hv[j] * mr[j * 64];
    for (int off = 32; off; off >>= 1) p += __shfl_xor(p, off, 64);
    sim[m] = p;
  }
  float mx = sim[0];
  for (int m = 1; m < 8; ++m) mx = fmaxf(mx, sim[m]);
  float s = 0.f;
  for (int m = 0; m < 8; ++m) { sim[m] = __expf(sim[m] - mx); s += sim[m]; }
  const float inv = 1.f / s;
  float outv[8] = {0.f,0.f,0.f,0.f,0.f,0.f,0.f,0.f};
  for (int m = 0; m < 8; ++m) {
    float w = sim[m] * inv;
    const float* mr = sm + m * 512 + lane;
    for (int j = 0; j < 8; ++j) outv[j] += w * mr[j * 64];
  }
  __bf16* hcrow = hc + (size_t)node * 1024 + colofs;
  for (int j = 0; j < 8; ++j) {
    __bf16 o = (__bf16)outv[j];
    hrow[lane + j * 64] = o;
    hcrow[lane + j * 64] = o;
  }
}

// ---------------- graph ranges (batch is sorted) ----------------
__global__ __launch_bounds__(256) void ranges_kernel(const int* __restrict__ batch,
                                                     int* __restrict__ gstart) {
  int g = blockIdx.x * 256 + threadIdx.x;
  if (g > N_GRAPH) return;
  if (g == N_GRAPH) { gstart[N_GRAPH] = N_NODES; return; }
  int lo = 0, hi = N_NODES;
  while (lo < hi) {
    int mid = (lo + hi) >> 1;
    if (batch[mid] < g) lo = mid + 1; else hi = mid;
  }
  gstart[g] = lo;
}

// ---------------- pooling phase 1: segmented max/sum over hc [N][1024] ----------------
__global__ __launch_bounds__(256) void pool1_kernel(const __bf16* __restrict__ hc,
                                                    const int* __restrict__ batch,
                                                    unsigned* __restrict__ gmax,
                                                    float* __restrict__ gsum) {
  __shared__ int bsh[128];
  const int r0 = blockIdx.x * 128;
  const int t = threadIdx.x;
  const int nrows = min(128, N_NODES - r0);
  if (t < nrows) bsh[t] = batch[r0 + t];
  __syncthreads();
  float mx[4] = {-3.0e38f, -3.0e38f, -3.0e38f, -3.0e38f};
  float sm[4] = {0.f, 0.f, 0.f, 0.f};
  int cur = -1;
  for (int r = 0; r < nrows; ++r) {
    int g = bsh[r];
    if (g != cur) {
      if (cur >= 0) {
#pragma unroll
        for (int j = 0; j < 4; ++j) {
          atomicMax(&gmax[(size_t)cur * 1024 + t * 4 + j], enc_f32(mx[j]));
          atomicAdd(&gsum[(size_t)cur * 1024 + t * 4 + j], sm[j]);
        }
      }
      cur = g;
#pragma unroll
      for (int j = 0; j < 4; ++j) { mx[j] = -3.0e38f; sm[j] = 0.f; }
    }
    bf16x4v v = *(const bf16x4v*)(hc + (size_t)(r0 + r) * 1024 + t * 4);
#pragma unroll
    for (int j = 0; j < 4; ++j) {
      float f = (float)v[j];
      mx[j] = fmaxf(mx[j], f);
      sm[j] += f;
    }
  }
  if (cur >= 0) {
#pragma unroll
    for (int j = 0; j < 4; ++j) {
      atomicMax(&gmax[(size_t)cur * 1024 + t * 4 + j], enc_f32(mx[j]));
      atomicAdd(&gsum[(size_t)cur * 1024 + t * 4 + j], sm[j]);
    }
  }
}

// ---------------- pooling phase 2: decode to gf [G][2048] = [max | mean] ----------------
__global__ __launch_bounds__(256) void pool2_kernel(const unsigned* __restrict__ gmax,
                                                    const float* __restrict__ gsum,
                                                    const int* __restrict__ gstart,
                                                    float* __restrict__ g) {
  const int gr = blockIdx.x;
  const int t = threadIdx.x;
  const int cnt = gstart[gr + 1] - gstart[gr];
  const float inv = 1.f / fmaxf((float)cnt, 1.f);
#pragma unroll
  for (int j = 0; j < 4; ++j) {
    const int f = t * 4 + j;
    unsigned u = gmax[(size_t)gr * 1024 + f];
    g[(size_t)gr * 2048 + f] = (cnt > 0) ? dec_f32(u) : 0.f;
    g[(size_t)gr * 2048 + 1024 + f] = gsum[(size_t)gr * 1024 + f] * inv;
  }
}

// ---------------- classifier head: log_softmax(g @ lin_w + lin_b) ----------------
__global__ __launch_bounds__(64) void classify_kernel(const float* __restrict__ g,
                                                      const float* __restrict__ lw,
                                                      const float* __restrict__ lb,
                                                      float* __restrict__ out) {
  const int gr = blockIdx.x;
  const int lane = threadIdx.x;   // 64
  float acc[10];
  for (int c = 0; c < 10; ++c) acc[c] = 0.f;
  const float* grow = g + (size_t)gr * 2048;
  for (int k = lane; k < 2048; k += 64) {
    float gv = grow[k];
    const float* w = lw + (size_t)k * 10;
#pragma unroll
    for (int c = 0; c < 10; ++c) acc[c] += gv * w[c];
  }
  for (int c = 0; c < 10; ++c)
    for (int off = 32; off; off >>= 1) acc[c] += __shfl_xor(acc[c], off, 64);
  if (lane == 0) {
    float lg[10];
    float mx = -3.0e38f;
    for (int c = 0; c < 10; ++c) { lg[c] = acc[c] + lb[c]; mx = fmaxf(mx, lg[c]); }
    float s = 0.f;
    for (int c = 0; c < 10; ++c) s += expf(lg[c] - mx);
    float lse = logf(s);
    for (int c = 0; c < 10; ++c) out[(size_t)gr * 10 + c] = lg[c] - mx - lse;
  }
}

// =======================================================================================
extern "C" void kernel_launch(void* const* d_in, const int* in_sizes, int n_in,
                              void* d_out, int out_size, void* d_ws, size_t ws_size,
                              hipStream_t stream) {
  (void)in_sizes; (void)n_in; (void)out_size; (void)ws_size;
  const float* x      = (const float*)d_in[0];
  const int*   eidx   = (const int*)d_in[1];
  const int*   batch  = (const int*)d_in[2];
  const float* pre_w  = (const float*)d_in[4];
  const float* pre_b  = (const float*)d_in[5];
  const float* w1_0   = (const float*)d_in[6];
  const float* b1_0   = (const float*)d_in[7];
  const float* w2_0   = (const float*)d_in[8];
  const float* b2_0   = (const float*)d_in[9];
  const float* mem_0  = (const float*)d_in[10];
  const float* w1_1   = (const float*)d_in[11];
  const float* b1_1   = (const float*)d_in[12];
  const float* w2_1   = (const float*)d_in[13];
  const float* b2_1   = (const float*)d_in[14];
  const float* mem_1  = (const float*)d_in[15];
  const float* lin_w  = (const float*)d_in[16];
  const float* lin_b  = (const float*)d_in[17];
  float* out = (float*)d_out;

  const int* src = eidx;
  const int* dst = eidx + N_EDGES;

  // ---- workspace carve ----
  char* p = (char*)d_ws;
  auto alloc = [&](size_t bytes) -> char* {
    char* r = p;
    p += (bytes + 255) & ~(size_t)255;
    return r;
  };
  __bf16* xb    = (__bf16*)alloc((size_t)MP * 512 * 2);
  __bf16* hb    = (__bf16*)alloc((size_t)MP * 512 * 2);
  __bf16* aggb  = (__bf16*)alloc((size_t)MP * 512 * 2);
  __bf16* y1b   = (__bf16*)alloc((size_t)MP * 512 * 2);
  __bf16* hcb   = (__bf16*)alloc((size_t)MP * 1024 * 2);
  __bf16* preT  = (__bf16*)alloc((size_t)512 * 512 * 2);
  __bf16* w1T0  = (__bf16*)alloc((size_t)512 * 1024 * 2);
  __bf16* w2T0  = (__bf16*)alloc((size_t)512 * 512 * 2);
  __bf16* w1T1  = (__bf16*)alloc((size_t)512 * 1024 * 2);
  __bf16* w2T1  = (__bf16*)alloc((size_t)512 * 512 * 2);
  int* deg      = (int*)alloc((size_t)N_NODES * 4);
  int* rowstart = (int*)alloc((size_t)(N_NODES + 1) * 4);
  int* cursor   = (int*)alloc((size_t)N_NODES * 4);
  int* bsum     = (int*)alloc(128 * 4);
  int* csr      = (int*)alloc((size_t)N_EDGES * 4);
  int* gstart   = (int*)alloc((size_t)(N_GRAPH + 1) * 4);
  float* gf     = (float*)alloc((size_t)N_GRAPH * 2048 * 4);
  unsigned* gmax = (unsigned*)alloc((size_t)N_GRAPH * 1024 * 4);
  float* gsum    = (float*)alloc((size_t)N_GRAPH * 1024 * 4);

  // ---- enable 128KB dynamic LDS for the GEMM instantiations (host-side, capture-safe) ----
  const int GEMM_LDS = 131072;
  hipFuncSetAttribute(reinterpret_cast<const void*>(&gemm8p_kernel<512,  false, false>),
                      hipFuncAttributeMaxDynamicSharedMemorySize, GEMM_LDS);
  hipFuncSetAttribute(reinterpret_cast<const void*>(&gemm8p_kernel<1024, true,  true>),
                      hipFuncAttributeMaxDynamicSharedMemorySize, GEMM_LDS);
  hipFuncSetAttribute(reinterpret_cast<const void*>(&gemm8p_kernel<512,  false, true>),
                      hipFuncAttributeMaxDynamicSharedMemorySize, GEMM_LDS);

  // ---- weight prep (bf16 transposed: BT[n][k]) ----
  transpose_kernel<<<dim3(16, 16), 256, 0, stream>>>(pre_w, preT, 512, 512);
  transpose_kernel<<<dim3(16, 32), 256, 0, stream>>>(w1_0, w1T0, 1024, 512);
  transpose_kernel<<<dim3(16, 16), 256, 0, stream>>>(w2_0, w2T0, 512, 512);
  transpose_kernel<<<dim3(16, 32), 256, 0, stream>>>(w1_1, w1T1, 1024, 512);
  transpose_kernel<<<dim3(16, 16), 256, 0, stream>>>(w2_1, w2T1, 512, 512);

  // ---- input cast ----
  castx_kernel<<<25024, 256, 0, stream>>>(x, xb);

  // ---- CSR build (per call; deterministic work) ----
  hipMemsetAsync(deg, 0, (size_t)N_NODES * 4, stream);
  degree_kernel<<<3125, 256, 0, stream>>>(dst, deg);
  scan1_kernel<<<98, 256, 0, stream>>>(deg, rowstart, bsum, N_NODES);
  scan2_kernel<<<1, 64, 0, stream>>>(bsum, 98);
  scan3_kernel<<<392, 256, 0, stream>>>(rowstart, bsum, cursor, N_NODES);
  scatter_kernel<<<3125, 256, 0, stream>>>(src, dst, cursor, csr);

  // pooling accumulators: gmax||gsum are contiguous -> one memset
  hipMemsetAsync(gmax, 0, (size_t)N_GRAPH * 1024 * 4 * 2, stream);
  ranges_kernel<<<2, 256, 0, stream>>>(batch, gstart);

  const int GG = 782;   // 391 M-tiles x 2 N-tiles

  // ---- pre conv: h = x @ pre_w + pre_b ----
  gemm8p_kernel<512, false, false><<<GG, 512, GEMM_LDS, stream>>>(xb, nullptr, preT, pre_b, hb);

  // ---- layer 0 ----
  aggregate_kernel<<<25000, 256, 0, stream>>>(hb, rowstart, csr, aggb);
  gemm8p_kernel<1024, true, true><<<GG, 512, GEMM_LDS, stream>>>(hb, aggb, w1T0, b1_0, y1b);
  gemm8p_kernel<512, false, true><<<GG, 512, GEMM_LDS, stream>>>(y1b, nullptr, w2T0, b2_0, hb);
  memmod_kernel<<<25000, 256, 0, stream>>>(hb, mem_0, hcb, 0);

  // ---- layer 1 ----
  aggregate_kernel<<<25000, 256, 0, stream>>>(hb, rowstart, csr, aggb);
  gemm8p_kernel<1024, true, true><<<GG, 512, GEMM_LDS, stream>>>(hb, aggb, w1T1, b1_1, y1b);
  gemm8p_kernel<512, false, true><<<GG, 512, GEMM_LDS, stream>>>(y1b, nullptr, w2T1, b2_1, hb);
  memmod_kernel<<<25000, 256, 0, stream>>>(hb, mem_1, hcb, 512);

  // ---- readout ----
  pool1_kernel<<<782, 256, 0, stream>>>(hcb, batch, gmax, gsum);
  pool2_kernel<<<N_GRAPH, 256, 0, stream>>>(gmax, gsum, gstart, gf);
  classify_kernel<<<N_GRAPH, 64, 0, stream>>>(gf, lin_w, lin_b, out);
}

// Round 7
// 1177.768 us; speedup vs baseline: 1.2630x; 1.0864x over previous
//
#include <hip/hip_runtime.h>

#define N_NODES 100000
#define N_EDGES 800000
#define N_GRAPH 256
#define MP      100096   // 391 * 256, padded M
#define NH      512

typedef __bf16 bf16x4v __attribute__((ext_vector_type(4)));
typedef __bf16 bf16x8v __attribute__((ext_vector_type(8)));
typedef float  f32x4   __attribute__((ext_vector_type(4)));

__device__ __forceinline__ void gload_lds16(const void* g, void* l) {
  __builtin_amdgcn_global_load_lds((const __attribute__((address_space(1))) void*)g,
                                   (__attribute__((address_space(3))) void*)l, 16, 0, 0);
}

// order-preserving fp32 <-> uint32 encoding for atomicMax
__device__ __forceinline__ unsigned enc_f32(float f) {
  unsigned u = __float_as_uint(f);
  return (u & 0x80000000u) ? ~u : (u | 0x80000000u);
}
__device__ __forceinline__ float dec_f32(unsigned u) {
  return (u & 0x80000000u) ? __uint_as_float(u & 0x7FFFFFFFu) : __uint_as_float(~u);
}

// ---------------- cast x (fp32) -> padded bf16 [MP][512] ----------------
__global__ __launch_bounds__(256) void castx_kernel(const float* __restrict__ x,
                                                    __bf16* __restrict__ xb) {
  const size_t i = (size_t)blockIdx.x * 256 + threadIdx.x;   // 8-elem chunk id
  const size_t row = i >> 6;
  const int c = (int)(i & 63) * 8;
  if (row >= MP) return;
  bf16x8v o;
  if (row < N_NODES) {
    const float* p = x + row * 512 + c;
    f32x4 a = *(const f32x4*)p;
    f32x4 b = *(const f32x4*)(p + 4);
    o[0]=(__bf16)a[0]; o[1]=(__bf16)a[1]; o[2]=(__bf16)a[2]; o[3]=(__bf16)a[3];
    o[4]=(__bf16)b[0]; o[5]=(__bf16)b[1]; o[6]=(__bf16)b[2]; o[7]=(__bf16)b[3];
  } else {
    for (int j = 0; j < 8; ++j) o[j] = (__bf16)0.0f;
  }
  *(bf16x8v*)(xb + row * 512 + c) = o;
}

// ---------------- weight transpose: W[K][N] fp32 -> BT[N][K] bf16 ----------------
__global__ __launch_bounds__(256) void transpose_kernel(const float* __restrict__ W,
                                                        __bf16* __restrict__ BT,
                                                        int K, int Nn) {
  __shared__ float tile[32][33];
  const int bx = blockIdx.x;   // n tile
  const int by = blockIdx.y;   // k tile
  const int tx = threadIdx.x & 31;
  const int ty = threadIdx.x >> 5;   // 0..7
  for (int j = 0; j < 4; ++j) {
    int k = by * 32 + ty + j * 8;
    int n = bx * 32 + tx;
    tile[ty + j * 8][tx] = W[(size_t)k * Nn + n];
  }
  __syncthreads();
  for (int j = 0; j < 4; ++j) {
    int n = bx * 32 + ty + j * 8;
    int k = by * 32 + tx;
    BT[(size_t)n * K + k] = (__bf16)tile[tx][ty + j * 8];
  }
}

// ---------------- CSR build ----------------
__global__ __launch_bounds__(256) void degree_kernel(const int* __restrict__ dst,
                                                     int* __restrict__ deg) {
  int e = blockIdx.x * 256 + threadIdx.x;
  if (e < N_EDGES) atomicAdd(&deg[dst[e]], 1);
}

__global__ __launch_bounds__(256) void scan1_kernel(const int* __restrict__ deg,
                                                    int* __restrict__ rs,
                                                    int* __restrict__ bsum, int n) {
  __shared__ int lds[256];
  const int b = blockIdx.x, t = threadIdx.x;
  const int base = b * 1024 + t * 4;
  int v[4];
  for (int j = 0; j < 4; ++j) v[j] = (base + j < n) ? deg[base + j] : 0;
  int tsum = v[0] + v[1] + v[2] + v[3];
  lds[t] = tsum;
  __syncthreads();
  for (int off = 1; off < 256; off <<= 1) {
    int x = 0;
    if (t >= off) x = lds[t - off];
    __syncthreads();
    lds[t] += x;
    __syncthreads();
  }
  int run = lds[t] - tsum;   // exclusive prefix of this thread
  for (int j = 0; j < 4; ++j) {
    if (base + j < n) rs[base + j] = run;
    run += v[j];
  }
  if (t == 255) bsum[b] = lds[255];
}

__global__ void scan2_kernel(int* bsum, int nb) {
  if (threadIdx.x == 0 && blockIdx.x == 0) {
    int run = 0;
    for (int i = 0; i < nb; ++i) { int v = bsum[i]; bsum[i] = run; run += v; }
  }
}

__global__ __launch_bounds__(256) void scan3_kernel(int* __restrict__ rs,
                                                    const int* __restrict__ bsum,
                                                    int* __restrict__ cursor, int n) {
  int i = blockIdx.x * 256 + threadIdx.x;
  if (i < n) {
    int v = rs[i] + bsum[i >> 10];
    rs[i] = v;
    cursor[i] = v;
  } else if (i == n) {
    rs[n] = N_EDGES;
  }
}

__global__ __launch_bounds__(256) void scatter_kernel(const int* __restrict__ src,
                                                      const int* __restrict__ dst,
                                                      int* __restrict__ cursor,
                                                      int* __restrict__ csr) {
  int e = blockIdx.x * 256 + threadIdx.x;
  if (e < N_EDGES) {
    int slot = atomicAdd(&cursor[dst[e]], 1);
    csr[slot] = src[e];
  }
}

// ---------------- aggregate: agg[n] = sum_{e: dst==n} h[src[e]]  (pull, CSR) ----------------
__global__ __launch_bounds__(256) void aggregate_kernel(const __bf16* __restrict__ h,
                                                        const int* __restrict__ rs,
                                                        const int* __restrict__ csr,
                                                        __bf16* __restrict__ agg) {
  const int node = blockIdx.x * 4 + (threadIdx.x >> 6);
  if (node >= N_NODES) return;
  const int lane = threadIdx.x & 63;
  const int s = rs[node], e = rs[node + 1];
  float acc[8] = {0.f,0.f,0.f,0.f,0.f,0.f,0.f,0.f};
  for (int i = s; i < e; ++i) {
    int sn = csr[i];
    bf16x8v v = *(const bf16x8v*)(h + (size_t)sn * 512 + lane * 8);
    for (int j = 0; j < 8; ++j) acc[j] += (float)v[j];
  }
  bf16x8v o;
  for (int j = 0; j < 8; ++j) o[j] = (__bf16)acc[j];
  *(bf16x8v*)(agg + (size_t)node * 512 + lane * 8) = o;
}

// ---------------- GEMM 256x256, BK=32, depth-3 prefetch ring pipeline (round-4 best) ----
// C[M][512] = relu?( A @ BT^T + bias ), bf16 in/out, fp32 acc.
// 512 threads = 8 waves (2M x 4N), per-wave output 128x64.
// LDS (dynamic, 128KB): As[4][256][32], Bs[4][256][32] -- 4-slot ring, prefetch depth 3.
// Counted vmcnt(8) per K-tile; ONE raw s_barrier per K-tile.
// Chunk swizzle: LDS[r][c] = G[r][c ^ ((r>>1)&3)] (inverse-swizzled source, swizzled read).
template<int KTOT, bool SPLIT, bool RELU>
__global__ __launch_bounds__(512, 2) void gemm256_kernel(const __bf16* __restrict__ A1,
                                                         const __bf16* __restrict__ A2,
                                                         const __bf16* __restrict__ BT,
                                                         const float* __restrict__ bias,
                                                         __bf16* __restrict__ C) {
  extern __shared__ char smem[];
  __bf16* As = (__bf16*)smem;              // 4 slots * 256*32 elems = 64KB
  __bf16* Bs = (__bf16*)(smem + 65536);    // 64KB
  const int tid  = threadIdx.x;
  const int wid  = tid >> 6;     // 0..7
  const int lane = tid & 63;
  const int wm = wid >> 2;       // 0..1
  const int wn = wid & 3;        // 0..3
  const int srow = tid >> 2;     // 0..127 (row within 128-row half)
  const int scol = ((tid & 3) ^ ((tid >> 3) & 3)) * 8;   // inverse-swizzled source chunk
  const int rl  = lane & 15;
  const int rdk = (((lane >> 4) ^ ((lane >> 1) & 3)) * 8);  // swizzled read chunk

  // XCD-aware bijective remap (782 = 6*98 + 2*97); pairs (tn=0,1) of a tm share an XCD
  const int bid = blockIdx.x;
  const int xcd = bid & 7, pos = bid >> 3;
  const int idx = (xcd < 6) ? (xcd * 98 + pos) : (588 + (xcd - 6) * 97 + pos);
  const int tm = idx >> 1, tn = idx & 1;

  constexpr int NT = KTOT / 32;

  f32x4 acc[8][4];
#pragma unroll
  for (int mi = 0; mi < 8; ++mi)
#pragma unroll
    for (int ni = 0; ni < 4; ++ni)
      acc[mi][ni] = f32x4{0.f, 0.f, 0.f, 0.f};

  auto stage = [&](int tk) {
    const int slot = tk & 3;
    const __bf16* Ap = A1;
    int kc = tk * 32;
    if (SPLIT && tk >= NT / 2) { Ap = A2; kc = (tk - NT / 2) * 32; }
#pragma unroll
    for (int j = 0; j < 2; ++j) {
      const __bf16* g = Ap + (size_t)(tm * 256 + j * 128 + srow) * NH + (kc + scol);
      gload_lds16(g, (char*)As + slot * 16384 + j * 8192 + wid * 1024);
    }
#pragma unroll
    for (int j = 0; j < 2; ++j) {
      const __bf16* g = BT + (size_t)(tn * 256 + j * 128 + srow) * KTOT + (tk * 32 + scol);
      gload_lds16(g, (char*)Bs + slot * 16384 + j * 8192 + wid * 1024);
    }
  };

  // prologue: fill 3 slots (12 loads in flight)
  stage(0); stage(1); stage(2);

  for (int tk = 0; tk < NT; ++tk) {
    if (tk < NT - 2)       asm volatile("s_waitcnt vmcnt(8)" ::: "memory");
    else if (tk == NT - 2) asm volatile("s_waitcnt vmcnt(4)" ::: "memory");
    else                   asm volatile("s_waitcnt vmcnt(0)" ::: "memory");
    __builtin_amdgcn_s_barrier();            // all waves: tile tk landed, tile tk-1 consumed
    asm volatile("" ::: "memory");           // pin LDS ops after the barrier

    if (tk + 3 < NT) stage(tk + 3);          // overwrites slot (tk-1)&3 -- safe post-barrier

    const int slot = tk & 3;
    const __bf16* a0 = As + slot * 8192 + (wm * 128 + rl) * 32 + rdk;
    const __bf16* b0 = Bs + slot * 8192 + (wn * 64 + rl) * 32 + rdk;
    bf16x8v av[8], bv[4];
#pragma unroll
    for (int mi = 0; mi < 8; ++mi) av[mi] = *(const bf16x8v*)(a0 + mi * 16 * 32);
#pragma unroll
    for (int ni = 0; ni < 4; ++ni) bv[ni] = *(const bf16x8v*)(b0 + ni * 16 * 32);

    __builtin_amdgcn_s_setprio(1);
#pragma unroll
    for (int mi = 0; mi < 8; ++mi)
#pragma unroll
      for (int ni = 0; ni < 4; ++ni)
        acc[mi][ni] = __builtin_amdgcn_mfma_f32_16x16x32_bf16(av[mi], bv[ni], acc[mi][ni], 0, 0, 0);
    __builtin_amdgcn_s_setprio(0);
  }

  // epilogue: bias (+ relu) -> bf16
  const int rg = (lane >> 4) * 4;
#pragma unroll
  for (int ni = 0; ni < 4; ++ni) {
    const int col = tn * 256 + wn * 64 + ni * 16 + rl;
    const float bv_ = bias[col];
#pragma unroll
    for (int mi = 0; mi < 8; ++mi) {
      const int rowb = tm * 256 + wm * 128 + mi * 16 + rg;
#pragma unroll
      for (int r = 0; r < 4; ++r) {
        float v = acc[mi][ni][r] + bv_;
        if (RELU) v = fmaxf(v, 0.f);
        C[(size_t)(rowb + r) * NH + col] = (__bf16)v;
      }
    }
  }
}

// ---------------- fused memory module + pooling -----------------------------------------
// Per node: h_new = softmax(h @ mem^T) @ mem  (identical math to the old memmod).
// WRITE_H: write h_new back to h (layer 0 feeds aggregate/w1 of layer 1).
// Pooling: wave owns 32 CONTIGUOUS nodes (batch sorted) -> running max/sum in registers,
// boundary-flush atomics to gmax/gsum[g*1024 + colofs + col]. hc buffer is eliminated.
template<bool WRITE_H>
__global__ __launch_bounds__(256) void memmod_pool_kernel(__bf16* __restrict__ h,
                                                          const float* __restrict__ mem,
                                                          const int* __restrict__ batch,
                                                          unsigned* __restrict__ gmax,
                                                          float* __restrict__ gsum,
                                                          int colofs) {
  __shared__ float sm[8 * 512];
  const int tid = threadIdx.x;
  for (int i = tid; i < 4096; i += 256) sm[i] = mem[i];
  __syncthreads();
  const int lane = tid & 63;
  const int n0 = blockIdx.x * 128 + (tid >> 6) * 32;
  const int nend = min(n0 + 32, N_NODES);

  float mx[8], sv[8];
#pragma unroll
  for (int j = 0; j < 8; ++j) { mx[j] = -3.0e38f; sv[j] = 0.f; }
  int cur = -1;

  for (int n = n0; n < nend; ++n) {
    const int g = batch[n];
    if (g != cur) {
      if (cur >= 0) {
#pragma unroll
        for (int j = 0; j < 8; ++j) {
          atomicMax(&gmax[(size_t)cur * 1024 + colofs + lane + j * 64], enc_f32(mx[j]));
          atomicAdd(&gsum[(size_t)cur * 1024 + colofs + lane + j * 64], sv[j]);
        }
      }
      cur = g;
#pragma unroll
      for (int j = 0; j < 8; ++j) { mx[j] = -3.0e38f; sv[j] = 0.f; }
    }
    __bf16* hrow = h + (size_t)n * 512;
    float hv[8];
#pragma unroll
    for (int j = 0; j < 8; ++j) hv[j] = (float)hrow[lane + j * 64];
    float simv[8];
#pragma unroll
    for (int m = 0; m < 8; ++m) {
      float p = 0.f;
      const float* mr = sm + m * 512 + lane;
#pragma unroll
      for (int j = 0; j < 8; ++j) p += hv[j] * mr[j * 64];
      for (int off = 32; off; off >>= 1) p += __shfl_xor(p, off, 64);
      simv[m] = p;
    }
    float smx = simv[0];
#pragma unroll
    for (int m = 1; m < 8; ++m) smx = fmaxf(smx, simv[m]);
    float ssum = 0.f;
#pragma unroll
    for (int m = 0; m < 8; ++m) { simv[m] = __expf(simv[m] - smx); ssum += simv[m]; }
    const float inv = 1.f / ssum;
    float outv[8] = {0.f,0.f,0.f,0.f,0.f,0.f,0.f,0.f};
#pragma unroll
    for (int m = 0; m < 8; ++m) {
      const float w = simv[m] * inv;
      const float* mr = sm + m * 512 + lane;
#pragma unroll
      for (int j = 0; j < 8; ++j) outv[j] += w * mr[j * 64];
    }
    if (WRITE_H) {
#pragma unroll
      for (int j = 0; j < 8; ++j) hrow[lane + j * 64] = (__bf16)outv[j];
    }
#pragma unroll
    for (int j = 0; j < 8; ++j) {
      mx[j] = fmaxf(mx[j], outv[j]);
      sv[j] += outv[j];
    }
  }
  if (cur >= 0) {
#pragma unroll
    for (int j = 0; j < 8; ++j) {
      atomicMax(&gmax[(size_t)cur * 1024 + colofs + lane + j * 64], enc_f32(mx[j]));
      atomicAdd(&gsum[(size_t)cur * 1024 + colofs + lane + j * 64], sv[j]);
    }
  }
}

// ---------------- graph ranges (batch is sorted) ----------------
__global__ __launch_bounds__(256) void ranges_kernel(const int* __restrict__ batch,
                                                     int* __restrict__ gstart) {
  int g = blockIdx.x * 256 + threadIdx.x;
  if (g > N_GRAPH) return;
  if (g == N_GRAPH) { gstart[N_GRAPH] = N_NODES; return; }
  int lo = 0, hi = N_NODES;
  while (lo < hi) {
    int mid = (lo + hi) >> 1;
    if (batch[mid] < g) lo = mid + 1; else hi = mid;
  }
  gstart[g] = lo;
}

// ---------------- pooling decode: gf [G][2048] = [max | mean] ----------------
__global__ __launch_bounds__(256) void pool2_kernel(const unsigned* __restrict__ gmax,
                                                    const float* __restrict__ gsum,
                                                    const int* __restrict__ gstart,
                                                    float* __restrict__ g) {
  const int gr = blockIdx.x;
  const int t = threadIdx.x;
  const int cnt = gstart[gr + 1] - gstart[gr];
  const float inv = 1.f / fmaxf((float)cnt, 1.f);
#pragma unroll
  for (int j = 0; j < 4; ++j) {
    const int f = t * 4 + j;
    unsigned u = gmax[(size_t)gr * 1024 + f];
    g[(size_t)gr * 2048 + f] = (cnt > 0) ? dec_f32(u) : 0.f;
    g[(size_t)gr * 2048 + 1024 + f] = gsum[(size_t)gr * 1024 + f] * inv;
  }
}

// ---------------- classifier head: log_softmax(g @ lin_w + lin_b) ----------------
__global__ __launch_bounds__(64) void classify_kernel(const float* __restrict__ g,
                                                      const float* __restrict__ lw,
                                                      const float* __restrict__ lb,
                                                      float* __restrict__ out) {
  const int gr = blockIdx.x;
  const int lane = threadIdx.x;   // 64
  float acc[10];
  for (int c = 0; c < 10; ++c) acc[c] = 0.f;
  const float* grow = g + (size_t)gr * 2048;
  for (int k = lane; k < 2048; k += 64) {
    float gv = grow[k];
    const float* w = lw + (size_t)k * 10;
#pragma unroll
    for (int c = 0; c < 10; ++c) acc[c] += gv * w[c];
  }
  for (int c = 0; c < 10; ++c)
    for (int off = 32; off; off >>= 1) acc[c] += __shfl_xor(acc[c], off, 64);
  if (lane == 0) {
    float lg[10];
    float mx = -3.0e38f;
    for (int c = 0; c < 10; ++c) { lg[c] = acc[c] + lb[c]; mx = fmaxf(mx, lg[c]); }
    float s = 0.f;
    for (int c = 0; c < 10; ++c) s += expf(lg[c] - mx);
    float lse = logf(s);
    for (int c = 0; c < 10; ++c) out[(size_t)gr * 10 + c] = lg[c] - mx - lse;
  }
}

// =======================================================================================
extern "C" void kernel_launch(void* const* d_in, const int* in_sizes, int n_in,
                              void* d_out, int out_size, void* d_ws, size_t ws_size,
                              hipStream_t stream) {
  (void)in_sizes; (void)n_in; (void)out_size; (void)ws_size;
  const float* x      = (const float*)d_in[0];
  const int*   eidx   = (const int*)d_in[1];
  const int*   batch  = (const int*)d_in[2];
  const float* pre_w  = (const float*)d_in[4];
  const float* pre_b  = (const float*)d_in[5];
  const float* w1_0   = (const float*)d_in[6];
  const float* b1_0   = (const float*)d_in[7];
  const float* w2_0   = (const float*)d_in[8];
  const float* b2_0   = (const float*)d_in[9];
  const float* mem_0  = (const float*)d_in[10];
  const float* w1_1   = (const float*)d_in[11];
  const float* b1_1   = (const float*)d_in[12];
  const float* w2_1   = (const float*)d_in[13];
  const float* b2_1   = (const float*)d_in[14];
  const float* mem_1  = (const float*)d_in[15];
  const float* lin_w  = (const float*)d_in[16];
  const float* lin_b  = (const float*)d_in[17];
  float* out = (float*)d_out;

  const int* src = eidx;
  const int* dst = eidx + N_EDGES;

  // ---- workspace carve ----
  char* p = (char*)d_ws;
  auto alloc = [&](size_t bytes) -> char* {
    char* r = p;
    p += (bytes + 255) & ~(size_t)255;
    return r;
  };
  __bf16* xb    = (__bf16*)alloc((size_t)MP * 512 * 2);
  __bf16* hb    = (__bf16*)alloc((size_t)MP * 512 * 2);
  __bf16* aggb  = (__bf16*)alloc((size_t)MP * 512 * 2);
  __bf16* y1b   = (__bf16*)alloc((size_t)MP * 512 * 2);
  __bf16* preT  = (__bf16*)alloc((size_t)512 * 512 * 2);
  __bf16* w1T0  = (__bf16*)alloc((size_t)512 * 1024 * 2);
  __bf16* w2T0  = (__bf16*)alloc((size_t)512 * 512 * 2);
  __bf16* w1T1  = (__bf16*)alloc((size_t)512 * 1024 * 2);
  __bf16* w2T1  = (__bf16*)alloc((size_t)512 * 512 * 2);
  int* deg      = (int*)alloc((size_t)N_NODES * 4);
  int* rowstart = (int*)alloc((size_t)(N_NODES + 1) * 4);
  int* cursor   = (int*)alloc((size_t)N_NODES * 4);
  int* bsum     = (int*)alloc(128 * 4);
  int* csr      = (int*)alloc((size_t)N_EDGES * 4);
  int* gstart   = (int*)alloc((size_t)(N_GRAPH + 1) * 4);
  float* gf     = (float*)alloc((size_t)N_GRAPH * 2048 * 4);
  unsigned* gmax = (unsigned*)alloc((size_t)N_GRAPH * 1024 * 4);
  float* gsum    = (float*)alloc((size_t)N_GRAPH * 1024 * 4);

  // ---- enable 128KB dynamic LDS for the GEMM instantiations (host-side, capture-safe) ----
  const int GEMM_LDS = 131072;
  hipFuncSetAttribute(reinterpret_cast<const void*>(&gemm256_kernel<512,  false, false>),
                      hipFuncAttributeMaxDynamicSharedMemorySize, GEMM_LDS);
  hipFuncSetAttribute(reinterpret_cast<const void*>(&gemm256_kernel<1024, true,  true>),
                      hipFuncAttributeMaxDynamicSharedMemorySize, GEMM_LDS);
  hipFuncSetAttribute(reinterpret_cast<const void*>(&gemm256_kernel<512,  false, true>),
                      hipFuncAttributeMaxDynamicSharedMemorySize, GEMM_LDS);

  // ---- weight prep (bf16 transposed: BT[n][k]) ----
  transpose_kernel<<<dim3(16, 16), 256, 0, stream>>>(pre_w, preT, 512, 512);
  transpose_kernel<<<dim3(16, 32), 256, 0, stream>>>(w1_0, w1T0, 1024, 512);
  transpose_kernel<<<dim3(16, 16), 256, 0, stream>>>(w2_0, w2T0, 512, 512);
  transpose_kernel<<<dim3(16, 32), 256, 0, stream>>>(w1_1, w1T1, 1024, 512);
  transpose_kernel<<<dim3(16, 16), 256, 0, stream>>>(w2_1, w2T1, 512, 512);

  // ---- input cast ----
  castx_kernel<<<25024, 256, 0, stream>>>(x, xb);

  // ---- CSR build (per call; deterministic work) ----
  hipMemsetAsync(deg, 0, (size_t)N_NODES * 4, stream);
  degree_kernel<<<3125, 256, 0, stream>>>(dst, deg);
  scan1_kernel<<<98, 256, 0, stream>>>(deg, rowstart, bsum, N_NODES);
  scan2_kernel<<<1, 64, 0, stream>>>(bsum, 98);
  scan3_kernel<<<392, 256, 0, stream>>>(rowstart, bsum, cursor, N_NODES);
  scatter_kernel<<<3125, 256, 0, stream>>>(src, dst, cursor, csr);

  // pooling accumulators: gmax||gsum are contiguous -> one memset
  hipMemsetAsync(gmax, 0, (size_t)N_GRAPH * 1024 * 4 * 2, stream);
  ranges_kernel<<<2, 256, 0, stream>>>(batch, gstart);

  const int GG = 782;   // 391 M-tiles x 2 N-tiles

  // ---- pre conv: h = x @ pre_w + pre_b ----
  gemm256_kernel<512, false, false><<<GG, 512, GEMM_LDS, stream>>>(xb, nullptr, preT, pre_b, hb);

  // ---- layer 0 ----
  aggregate_kernel<<<25000, 256, 0, stream>>>(hb, rowstart, csr, aggb);
  gemm256_kernel<1024, true, true><<<GG, 512, GEMM_LDS, stream>>>(hb, aggb, w1T0, b1_0, y1b);
  gemm256_kernel<512, false, true><<<GG, 512, GEMM_LDS, stream>>>(y1b, nullptr, w2T0, b2_0, hb);
  memmod_pool_kernel<true><<<782, 256, 0, stream>>>(hb, mem_0, batch, gmax, gsum, 0);

  // ---- layer 1 ----
  aggregate_kernel<<<25000, 256, 0, stream>>>(hb, rowstart, csr, aggb);
  gemm256_kernel<1024, true, true><<<GG, 512, GEMM_LDS, stream>>>(hb, aggb, w1T1, b1_1, y1b);
  gemm256_kernel<512, false, true><<<GG, 512, GEMM_LDS, stream>>>(y1b, nullptr, w2T1, b2_1, hb);
  memmod_pool_kernel<false><<<782, 256, 0, stream>>>(hb, mem_1, batch, gmax, gsum, 512);

  // ---- readout ----
  pool2_kernel<<<N_GRAPH, 256, 0, stream>>>(gmax, gsum, gstart, gf);
  classify_kernel<<<N_GRAPH, 64, 0, stream>>>(gf, lin_w, lin_b, out);
}

// Round 8
// 1018.152 us; speedup vs baseline: 1.4610x; 1.1568x over previous
//
#include <hip/hip_runtime.h>

#define N_NODES 100000
#define N_EDGES 800000
#define N_GRAPH 256
#define MP      100096   // 391 * 256, padded M
#define NH      512

typedef __bf16 bf16x4v __attribute__((ext_vector_type(4)));
typedef __bf16 bf16x8v __attribute__((ext_vector_type(8)));
typedef float  f32x4   __attribute__((ext_vector_type(4)));

__device__ __forceinline__ void gload_lds16(const void* g, void* l) {
  __builtin_amdgcn_global_load_lds((const __attribute__((address_space(1))) void*)g,
                                   (__attribute__((address_space(3))) void*)l, 16, 0, 0);
}

// order-preserving fp32 <-> uint32 encoding for atomicMax
__device__ __forceinline__ unsigned enc_f32(float f) {
  unsigned u = __float_as_uint(f);
  return (u & 0x80000000u) ? ~u : (u | 0x80000000u);
}
__device__ __forceinline__ float dec_f32(unsigned u) {
  return (u & 0x80000000u) ? __uint_as_float(u & 0x7FFFFFFFu) : __uint_as_float(~u);
}

// ---------------- cast x (fp32) -> padded bf16 [MP][512] ----------------
__global__ __launch_bounds__(256) void castx_kernel(const float* __restrict__ x,
                                                    __bf16* __restrict__ xb) {
  const size_t i = (size_t)blockIdx.x * 256 + threadIdx.x;   // 8-elem chunk id
  const size_t row = i >> 6;
  const int c = (int)(i & 63) * 8;
  if (row >= MP) return;
  bf16x8v o;
  if (row < N_NODES) {
    const float* p = x + row * 512 + c;
    f32x4 a = *(const f32x4*)p;
    f32x4 b = *(const f32x4*)(p + 4);
    o[0]=(__bf16)a[0]; o[1]=(__bf16)a[1]; o[2]=(__bf16)a[2]; o[3]=(__bf16)a[3];
    o[4]=(__bf16)b[0]; o[5]=(__bf16)b[1]; o[6]=(__bf16)b[2]; o[7]=(__bf16)b[3];
  } else {
    for (int j = 0; j < 8; ++j) o[j] = (__bf16)0.0f;
  }
  *(bf16x8v*)(xb + row * 512 + c) = o;
}

// ---------------- weight transpose: W[K][N] fp32 -> BT[N][K] bf16 ----------------
__global__ __launch_bounds__(256) void transpose_kernel(const float* __restrict__ W,
                                                        __bf16* __restrict__ BT,
                                                        int K, int Nn) {
  __shared__ float tile[32][33];
  const int bx = blockIdx.x;   // n tile
  const int by = blockIdx.y;   // k tile
  const int tx = threadIdx.x & 31;
  const int ty = threadIdx.x >> 5;   // 0..7
  for (int j = 0; j < 4; ++j) {
    int k = by * 32 + ty + j * 8;
    int n = bx * 32 + tx;
    tile[ty + j * 8][tx] = W[(size_t)k * Nn + n];
  }
  __syncthreads();
  for (int j = 0; j < 4; ++j) {
    int n = bx * 32 + ty + j * 8;
    int k = by * 32 + tx;
    BT[(size_t)n * K + k] = (__bf16)tile[tx][ty + j * 8];
  }
}

// ---------------- CSR build ----------------
__global__ __launch_bounds__(256) void degree_kernel(const int* __restrict__ dst,
                                                     int* __restrict__ deg) {
  int e = blockIdx.x * 256 + threadIdx.x;
  if (e < N_EDGES) atomicAdd(&deg[dst[e]], 1);
}

__global__ __launch_bounds__(256) void scan1_kernel(const int* __restrict__ deg,
                                                    int* __restrict__ rs,
                                                    int* __restrict__ bsum, int n) {
  __shared__ int lds[256];
  const int b = blockIdx.x, t = threadIdx.x;
  const int base = b * 1024 + t * 4;
  int v[4];
  for (int j = 0; j < 4; ++j) v[j] = (base + j < n) ? deg[base + j] : 0;
  int tsum = v[0] + v[1] + v[2] + v[3];
  lds[t] = tsum;
  __syncthreads();
  for (int off = 1; off < 256; off <<= 1) {
    int x = 0;
    if (t >= off) x = lds[t - off];
    __syncthreads();
    lds[t] += x;
    __syncthreads();
  }
  int run = lds[t] - tsum;   // exclusive prefix of this thread
  for (int j = 0; j < 4; ++j) {
    if (base + j < n) rs[base + j] = run;
    run += v[j];
  }
  if (t == 255) bsum[b] = lds[255];
}

__global__ void scan2_kernel(int* bsum, int nb) {
  if (threadIdx.x == 0 && blockIdx.x == 0) {
    int run = 0;
    for (int i = 0; i < nb; ++i) { int v = bsum[i]; bsum[i] = run; run += v; }
  }
}

__global__ __launch_bounds__(256) void scan3_kernel(int* __restrict__ rs,
                                                    const int* __restrict__ bsum,
                                                    int* __restrict__ cursor, int n) {
  int i = blockIdx.x * 256 + threadIdx.x;
  if (i < n) {
    int v = rs[i] + bsum[i >> 10];
    rs[i] = v;
    cursor[i] = v;
  } else if (i == n) {
    rs[n] = N_EDGES;
  }
}

__global__ __launch_bounds__(256) void scatter_kernel(const int* __restrict__ src,
                                                      const int* __restrict__ dst,
                                                      int* __restrict__ cursor,
                                                      int* __restrict__ csr) {
  int e = blockIdx.x * 256 + threadIdx.x;
  if (e < N_EDGES) {
    int slot = atomicAdd(&cursor[dst[e]], 1);
    csr[slot] = src[e];
  }
}

// ---------------- aggregate (layer 0): agg[n] = sum_{e: dst==n} h[src[e]] ----------------
__global__ __launch_bounds__(256) void aggregate_kernel(const __bf16* __restrict__ h,
                                                        const int* __restrict__ rs,
                                                        const int* __restrict__ csr,
                                                        __bf16* __restrict__ agg) {
  const int node = blockIdx.x * 4 + (threadIdx.x >> 6);
  if (node >= N_NODES) return;
  const int lane = threadIdx.x & 63;
  const int s = rs[node], e = rs[node + 1];
  float acc[8] = {0.f,0.f,0.f,0.f,0.f,0.f,0.f,0.f};
  for (int i = s; i < e; ++i) {
    int sn = csr[i];
    bf16x8v v = *(const bf16x8v*)(h + (size_t)sn * 512 + lane * 8);
    for (int j = 0; j < 8; ++j) acc[j] += (float)v[j];
  }
  bf16x8v o;
  for (int j = 0; j < 8; ++j) o[j] = (__bf16)acc[j];
  *(bf16x8v*)(agg + (size_t)node * 512 + lane * 8) = o;
}

// ---------------- aggregate (layer 1, rank-8): aggS[n] = sum sim0[src] ----------------
__global__ __launch_bounds__(256) void aggsim_kernel(const float* __restrict__ sim,
                                                     const int* __restrict__ rs,
                                                     const int* __restrict__ csr,
                                                     float* __restrict__ aggS) {
  const int node = blockIdx.x * 256 + threadIdx.x;
  if (node >= N_NODES) return;
  f32x4 a0 = f32x4{0.f,0.f,0.f,0.f}, a1 = f32x4{0.f,0.f,0.f,0.f};
  const int s = rs[node], e = rs[node + 1];
  for (int i = s; i < e; ++i) {
    const int sn = csr[i];
    a0 += *(const f32x4*)(sim + (size_t)sn * 8);
    a1 += *(const f32x4*)(sim + (size_t)sn * 8 + 4);
  }
  *(f32x4*)(aggS + (size_t)node * 8) = a0;
  *(f32x4*)(aggS + (size_t)node * 8 + 4) = a1;
}

// ---------------- UV: U[m] = mem0[m] @ W1_1[0:512], V[m] = mem0[m] @ W1_1[512:1024] -----
// UV layout [16][512] fp32: rows 0..7 = U, 8..15 = V.
__global__ __launch_bounds__(512) void uv_kernel(const float* __restrict__ mem,
                                                 const float* __restrict__ w1,
                                                 float* __restrict__ UV) {
  const int mu = blockIdx.x;        // 0..15
  const int c  = threadIdx.x;       // 0..511
  const int m = mu & 7, half = mu >> 3;
  const float* wbase = w1 + (size_t)(half * 512) * 512;
  const float* mrow  = mem + (size_t)m * 512;
  float acc = 0.f;
  for (int k = 0; k < 512; ++k) acc += mrow[k] * wbase[(size_t)k * 512 + c];
  UV[(size_t)mu * 512 + c] = acc;
}

// ---------------- z1y: y1 = relu(sim0 @ U + aggS @ V + b1), [N,512] bf16 ----------------
__global__ __launch_bounds__(256) void z1y_kernel(const float* __restrict__ sim,
                                                  const float* __restrict__ aggS,
                                                  const float* __restrict__ UV,
                                                  const float* __restrict__ b1,
                                                  __bf16* __restrict__ y) {
  __shared__ float suv[16 * 512];   // 32KB
  __shared__ float sb[512];
  const int tid = threadIdx.x;
  for (int i = tid; i < 8192; i += 256) suv[i] = UV[i];
  for (int i = tid; i < 512; i += 256) sb[i] = b1[i];
  __syncthreads();
  const int node = blockIdx.x * 4 + (tid >> 6);
  if (node >= N_NODES) return;
  const int lane = tid & 63;
  f32x4 s0 = *(const f32x4*)(sim + (size_t)node * 8);
  f32x4 s1 = *(const f32x4*)(sim + (size_t)node * 8 + 4);
  f32x4 a0 = *(const f32x4*)(aggS + (size_t)node * 8);
  f32x4 a1 = *(const f32x4*)(aggS + (size_t)node * 8 + 4);
  float sv[8] = {s0[0],s0[1],s0[2],s0[3],s1[0],s1[1],s1[2],s1[3]};
  float av[8] = {a0[0],a0[1],a0[2],a0[3],a1[0],a1[1],a1[2],a1[3]};
  __bf16* yrow = y + (size_t)node * 512;
#pragma unroll
  for (int j = 0; j < 8; ++j) {
    const int c = lane + j * 64;
    float acc = sb[c];
#pragma unroll
    for (int m = 0; m < 8; ++m) {
      acc += sv[m] * suv[m * 512 + c];
      acc += av[m] * suv[(8 + m) * 512 + c];
    }
    yrow[c] = (__bf16)fmaxf(acc, 0.f);
  }
}

// ---------------- GEMM 256x256, BK=32, depth-3 prefetch ring pipeline (round-4 best) ----
template<int KTOT, bool SPLIT, bool RELU>
__global__ __launch_bounds__(512, 2) void gemm256_kernel(const __bf16* __restrict__ A1,
                                                         const __bf16* __restrict__ A2,
                                                         const __bf16* __restrict__ BT,
                                                         const float* __restrict__ bias,
                                                         __bf16* __restrict__ C) {
  extern __shared__ char smem[];
  __bf16* As = (__bf16*)smem;              // 4 slots * 256*32 elems = 64KB
  __bf16* Bs = (__bf16*)(smem + 65536);    // 64KB
  const int tid  = threadIdx.x;
  const int wid  = tid >> 6;     // 0..7
  const int lane = tid & 63;
  const int wm = wid >> 2;       // 0..1
  const int wn = wid & 3;        // 0..3
  const int srow = tid >> 2;     // 0..127 (row within 128-row half)
  const int scol = ((tid & 3) ^ ((tid >> 3) & 3)) * 8;   // inverse-swizzled source chunk
  const int rl  = lane & 15;
  const int rdk = (((lane >> 4) ^ ((lane >> 1) & 3)) * 8);  // swizzled read chunk

  // XCD-aware bijective remap (782 = 6*98 + 2*97); pairs (tn=0,1) of a tm share an XCD
  const int bid = blockIdx.x;
  const int xcd = bid & 7, pos = bid >> 3;
  const int idx = (xcd < 6) ? (xcd * 98 + pos) : (588 + (xcd - 6) * 97 + pos);
  const int tm = idx >> 1, tn = idx & 1;

  constexpr int NT = KTOT / 32;

  f32x4 acc[8][4];
#pragma unroll
  for (int mi = 0; mi < 8; ++mi)
#pragma unroll
    for (int ni = 0; ni < 4; ++ni)
      acc[mi][ni] = f32x4{0.f, 0.f, 0.f, 0.f};

  auto stage = [&](int tk) {
    const int slot = tk & 3;
    const __bf16* Ap = A1;
    int kc = tk * 32;
    if (SPLIT && tk >= NT / 2) { Ap = A2; kc = (tk - NT / 2) * 32; }
#pragma unroll
    for (int j = 0; j < 2; ++j) {
      const __bf16* g = Ap + (size_t)(tm * 256 + j * 128 + srow) * NH + (kc + scol);
      gload_lds16(g, (char*)As + slot * 16384 + j * 8192 + wid * 1024);
    }
#pragma unroll
    for (int j = 0; j < 2; ++j) {
      const __bf16* g = BT + (size_t)(tn * 256 + j * 128 + srow) * KTOT + (tk * 32 + scol);
      gload_lds16(g, (char*)Bs + slot * 16384 + j * 8192 + wid * 1024);
    }
  };

  // prologue: fill 3 slots (12 loads in flight)
  stage(0); stage(1); stage(2);

  for (int tk = 0; tk < NT; ++tk) {
    if (tk < NT - 2)       asm volatile("s_waitcnt vmcnt(8)" ::: "memory");
    else if (tk == NT - 2) asm volatile("s_waitcnt vmcnt(4)" ::: "memory");
    else                   asm volatile("s_waitcnt vmcnt(0)" ::: "memory");
    __builtin_amdgcn_s_barrier();            // all waves: tile tk landed, tile tk-1 consumed
    asm volatile("" ::: "memory");           // pin LDS ops after the barrier

    if (tk + 3 < NT) stage(tk + 3);          // overwrites slot (tk-1)&3 -- safe post-barrier

    const int slot = tk & 3;
    const __bf16* a0 = As + slot * 8192 + (wm * 128 + rl) * 32 + rdk;
    const __bf16* b0 = Bs + slot * 8192 + (wn * 64 + rl) * 32 + rdk;
    bf16x8v av[8], bv[4];
#pragma unroll
    for (int mi = 0; mi < 8; ++mi) av[mi] = *(const bf16x8v*)(a0 + mi * 16 * 32);
#pragma unroll
    for (int ni = 0; ni < 4; ++ni) bv[ni] = *(const bf16x8v*)(b0 + ni * 16 * 32);

    __builtin_amdgcn_s_setprio(1);
#pragma unroll
    for (int mi = 0; mi < 8; ++mi)
#pragma unroll
      for (int ni = 0; ni < 4; ++ni)
        acc[mi][ni] = __builtin_amdgcn_mfma_f32_16x16x32_bf16(av[mi], bv[ni], acc[mi][ni], 0, 0, 0);
    __builtin_amdgcn_s_setprio(0);
  }

  // epilogue: bias (+ relu) -> bf16
  const int rg = (lane >> 4) * 4;
#pragma unroll
  for (int ni = 0; ni < 4; ++ni) {
    const int col = tn * 256 + wn * 64 + ni * 16 + rl;
    const float bv_ = bias[col];
#pragma unroll
    for (int mi = 0; mi < 8; ++mi) {
      const int rowb = tm * 256 + wm * 128 + mi * 16 + rg;
#pragma unroll
      for (int r = 0; r < 4; ++r) {
        float v = acc[mi][ni][r] + bv_;
        if (RELU) v = fmaxf(v, 0.f);
        C[(size_t)(rowb + r) * NH + col] = (__bf16)v;
      }
    }
  }
}

// ---------------- layer-0 memmod: sim0 = softmax(h @ mem^T); pool h_new; write sim0 ------
// h_new = sim0 @ mem computed in-register for pooling only (never materialized).
__global__ __launch_bounds__(256) void memmod_pool_sim_kernel(const __bf16* __restrict__ h,
                                                              const float* __restrict__ mem,
                                                              const int* __restrict__ batch,
                                                              unsigned* __restrict__ gmax,
                                                              float* __restrict__ gsum,
                                                              float* __restrict__ simout) {
  __shared__ float sm[8 * 512];
  const int tid = threadIdx.x;
  for (int i = tid; i < 4096; i += 256) sm[i] = mem[i];
  __syncthreads();
  const int lane = tid & 63;
  const int n0 = blockIdx.x * 128 + (tid >> 6) * 32;
  const int nend = min(n0 + 32, N_NODES);

  float mx[8], sv[8];
#pragma unroll
  for (int j = 0; j < 8; ++j) { mx[j] = -3.0e38f; sv[j] = 0.f; }
  int cur = -1;

  for (int n = n0; n < nend; ++n) {
    const int g = batch[n];
    if (g != cur) {
      if (cur >= 0) {
#pragma unroll
        for (int j = 0; j < 8; ++j) {
          atomicMax(&gmax[(size_t)cur * 1024 + lane + j * 64], enc_f32(mx[j]));
          atomicAdd(&gsum[(size_t)cur * 1024 + lane + j * 64], sv[j]);
        }
      }
      cur = g;
#pragma unroll
      for (int j = 0; j < 8; ++j) { mx[j] = -3.0e38f; sv[j] = 0.f; }
    }
    const __bf16* hrow = h + (size_t)n * 512;
    float hv[8];
#pragma unroll
    for (int j = 0; j < 8; ++j) hv[j] = (float)hrow[lane + j * 64];
    float simv[8];
#pragma unroll
    for (int m = 0; m < 8; ++m) {
      float p = 0.f;
      const float* mr = sm + m * 512 + lane;
#pragma unroll
      for (int j = 0; j < 8; ++j) p += hv[j] * mr[j * 64];
      for (int off = 32; off; off >>= 1) p += __shfl_xor(p, off, 64);
      simv[m] = p;
    }
    float smx = simv[0];
#pragma unroll
    for (int m = 1; m < 8; ++m) smx = fmaxf(smx, simv[m]);
    float ssum = 0.f;
#pragma unroll
    for (int m = 0; m < 8; ++m) { simv[m] = __expf(simv[m] - smx); ssum += simv[m]; }
    const float inv = 1.f / ssum;
#pragma unroll
    for (int m = 0; m < 8; ++m) simv[m] *= inv;    // normalized probabilities
    if (lane == 0) {
      f32x4 w0{simv[0], simv[1], simv[2], simv[3]};
      f32x4 w1{simv[4], simv[5], simv[6], simv[7]};
      *(f32x4*)(simout + (size_t)n * 8) = w0;
      *(f32x4*)(simout + (size_t)n * 8 + 4) = w1;
    }
    float outv[8] = {0.f,0.f,0.f,0.f,0.f,0.f,0.f,0.f};
#pragma unroll
    for (int m = 0; m < 8; ++m) {
      const float w = simv[m];
      const float* mr = sm + m * 512 + lane;
#pragma unroll
      for (int j = 0; j < 8; ++j) outv[j] += w * mr[j * 64];
    }
#pragma unroll
    for (int j = 0; j < 8; ++j) {
      mx[j] = fmaxf(mx[j], outv[j]);
      sv[j] += outv[j];
    }
  }
  if (cur >= 0) {
#pragma unroll
    for (int j = 0; j < 8; ++j) {
      atomicMax(&gmax[(size_t)cur * 1024 + lane + j * 64], enc_f32(mx[j]));
      atomicAdd(&gsum[(size_t)cur * 1024 + lane + j * 64], sv[j]);
    }
  }
}

// ---------------- layer-1 memmod+pool (reads h, pools slice at colofs) ------------------
__global__ __launch_bounds__(256) void memmod_pool_kernel(const __bf16* __restrict__ h,
                                                          const float* __restrict__ mem,
                                                          const int* __restrict__ batch,
                                                          unsigned* __restrict__ gmax,
                                                          float* __restrict__ gsum,
                                                          int colofs) {
  __shared__ float sm[8 * 512];
  const int tid = threadIdx.x;
  for (int i = tid; i < 4096; i += 256) sm[i] = mem[i];
  __syncthreads();
  const int lane = tid & 63;
  const int n0 = blockIdx.x * 128 + (tid >> 6) * 32;
  const int nend = min(n0 + 32, N_NODES);

  float mx[8], sv[8];
#pragma unroll
  for (int j = 0; j < 8; ++j) { mx[j] = -3.0e38f; sv[j] = 0.f; }
  int cur = -1;

  for (int n = n0; n < nend; ++n) {
    const int g = batch[n];
    if (g != cur) {
      if (cur >= 0) {
#pragma unroll
        for (int j = 0; j < 8; ++j) {
          atomicMax(&gmax[(size_t)cur * 1024 + colofs + lane + j * 64], enc_f32(mx[j]));
          atomicAdd(&gsum[(size_t)cur * 1024 + colofs + lane + j * 64], sv[j]);
        }
      }
      cur = g;
#pragma unroll
      for (int j = 0; j < 8; ++j) { mx[j] = -3.0e38f; sv[j] = 0.f; }
    }
    const __bf16* hrow = h + (size_t)n * 512;
    float hv[8];
#pragma unroll
    for (int j = 0; j < 8; ++j) hv[j] = (float)hrow[lane + j * 64];
    float simv[8];
#pragma unroll
    for (int m = 0; m < 8; ++m) {
      float p = 0.f;
      const float* mr = sm + m * 512 + lane;
#pragma unroll
      for (int j = 0; j < 8; ++j) p += hv[j] * mr[j * 64];
      for (int off = 32; off; off >>= 1) p += __shfl_xor(p, off, 64);
      simv[m] = p;
    }
    float smx = simv[0];
#pragma unroll
    for (int m = 1; m < 8; ++m) smx = fmaxf(smx, simv[m]);
    float ssum = 0.f;
#pragma unroll
    for (int m = 0; m < 8; ++m) { simv[m] = __expf(simv[m] - smx); ssum += simv[m]; }
    const float inv = 1.f / ssum;
    float outv[8] = {0.f,0.f,0.f,0.f,0.f,0.f,0.f,0.f};
#pragma unroll
    for (int m = 0; m < 8; ++m) {
      const float w = simv[m] * inv;
      const float* mr = sm + m * 512 + lane;
#pragma unroll
      for (int j = 0; j < 8; ++j) outv[j] += w * mr[j * 64];
    }
#pragma unroll
    for (int j = 0; j < 8; ++j) {
      mx[j] = fmaxf(mx[j], outv[j]);
      sv[j] += outv[j];
    }
  }
  if (cur >= 0) {
#pragma unroll
    for (int j = 0; j < 8; ++j) {
      atomicMax(&gmax[(size_t)cur * 1024 + colofs + lane + j * 64], enc_f32(mx[j]));
      atomicAdd(&gsum[(size_t)cur * 1024 + colofs + lane + j * 64], sv[j]);
    }
  }
}

// ---------------- graph ranges (batch is sorted) ----------------
__global__ __launch_bounds__(256) void ranges_kernel(const int* __restrict__ batch,
                                                     int* __restrict__ gstart) {
  int g = blockIdx.x * 256 + threadIdx.x;
  if (g > N_GRAPH) return;
  if (g == N_GRAPH) { gstart[N_GRAPH] = N_NODES; return; }
  int lo = 0, hi = N_NODES;
  while (lo < hi) {
    int mid = (lo + hi) >> 1;
    if (batch[mid] < g) lo = mid + 1; else hi = mid;
  }
  gstart[g] = lo;
}

// ---------------- pooling decode: gf [G][2048] = [max | mean] ----------------
__global__ __launch_bounds__(256) void pool2_kernel(const unsigned* __restrict__ gmax,
                                                    const float* __restrict__ gsum,
                                                    const int* __restrict__ gstart,
                                                    float* __restrict__ g) {
  const int gr = blockIdx.x;
  const int t = threadIdx.x;
  const int cnt = gstart[gr + 1] - gstart[gr];
  const float inv = 1.f / fmaxf((float)cnt, 1.f);
#pragma unroll
  for (int j = 0; j < 4; ++j) {
    const int f = t * 4 + j;
    unsigned u = gmax[(size_t)gr * 1024 + f];
    g[(size_t)gr * 2048 + f] = (cnt > 0) ? dec_f32(u) : 0.f;
    g[(size_t)gr * 2048 + 1024 + f] = gsum[(size_t)gr * 1024 + f] * inv;
  }
}

// ---------------- classifier head: log_softmax(g @ lin_w + lin_b) ----------------
__global__ __launch_bounds__(64) void classify_kernel(const float* __restrict__ g,
                                                      const float* __restrict__ lw,
                                                      const float* __restrict__ lb,
                                                      float* __restrict__ out) {
  const int gr = blockIdx.x;
  const int lane = threadIdx.x;   // 64
  float acc[10];
  for (int c = 0; c < 10; ++c) acc[c] = 0.f;
  const float* grow = g + (size_t)gr * 2048;
  for (int k = lane; k < 2048; k += 64) {
    float gv = grow[k];
    const float* w = lw + (size_t)k * 10;
#pragma unroll
    for (int c = 0; c < 10; ++c) acc[c] += gv * w[c];
  }
  for (int c = 0; c < 10; ++c)
    for (int off = 32; off; off >>= 1) acc[c] += __shfl_xor(acc[c], off, 64);
  if (lane == 0) {
    float lg[10];
    float mx = -3.0e38f;
    for (int c = 0; c < 10; ++c) { lg[c] = acc[c] + lb[c]; mx = fmaxf(mx, lg[c]); }
    float s = 0.f;
    for (int c = 0; c < 10; ++c) s += expf(lg[c] - mx);
    float lse = logf(s);
    for (int c = 0; c < 10; ++c) out[(size_t)gr * 10 + c] = lg[c] - mx - lse;
  }
}

// =======================================================================================
extern "C" void kernel_launch(void* const* d_in, const int* in_sizes, int n_in,
                              void* d_out, int out_size, void* d_ws, size_t ws_size,
                              hipStream_t stream) {
  (void)in_sizes; (void)n_in; (void)out_size; (void)ws_size;
  const float* x      = (const float*)d_in[0];
  const int*   eidx   = (const int*)d_in[1];
  const int*   batch  = (const int*)d_in[2];
  const float* pre_w  = (const float*)d_in[4];
  const float* pre_b  = (const float*)d_in[5];
  const float* w1_0   = (const float*)d_in[6];
  const float* b1_0   = (const float*)d_in[7];
  const float* w2_0   = (const float*)d_in[8];
  const float* b2_0   = (const float*)d_in[9];
  const float* mem_0  = (const float*)d_in[10];
  const float* w1_1   = (const float*)d_in[11];
  const float* b1_1   = (const float*)d_in[12];
  const float* w2_1   = (const float*)d_in[13];
  const float* b2_1   = (const float*)d_in[14];
  const float* mem_1  = (const float*)d_in[15];
  const float* lin_w  = (const float*)d_in[16];
  const float* lin_b  = (const float*)d_in[17];
  float* out = (float*)d_out;

  const int* src = eidx;
  const int* dst = eidx + N_EDGES;

  // ---- workspace carve ----
  char* p = (char*)d_ws;
  auto alloc = [&](size_t bytes) -> char* {
    char* r = p;
    p += (bytes + 255) & ~(size_t)255;
    return r;
  };
  __bf16* xb    = (__bf16*)alloc((size_t)MP * 512 * 2);
  __bf16* hb    = (__bf16*)alloc((size_t)MP * 512 * 2);
  __bf16* aggb  = (__bf16*)alloc((size_t)MP * 512 * 2);
  __bf16* y1b   = (__bf16*)alloc((size_t)MP * 512 * 2);
  __bf16* preT  = (__bf16*)alloc((size_t)512 * 512 * 2);
  __bf16* w1T0  = (__bf16*)alloc((size_t)512 * 1024 * 2);
  __bf16* w2T0  = (__bf16*)alloc((size_t)512 * 512 * 2);
  __bf16* w2T1  = (__bf16*)alloc((size_t)512 * 512 * 2);
  int* deg      = (int*)alloc((size_t)N_NODES * 4);
  int* rowstart = (int*)alloc((size_t)(N_NODES + 1) * 4);
  int* cursor   = (int*)alloc((size_t)N_NODES * 4);
  int* bsum     = (int*)alloc(128 * 4);
  int* csr      = (int*)alloc((size_t)N_EDGES * 4);
  int* gstart   = (int*)alloc((size_t)(N_GRAPH + 1) * 4);
  float* gf     = (float*)alloc((size_t)N_GRAPH * 2048 * 4);
  unsigned* gmax = (unsigned*)alloc((size_t)N_GRAPH * 1024 * 4);
  float* gsum    = (float*)alloc((size_t)N_GRAPH * 1024 * 4);
  float* sim0    = (float*)alloc((size_t)N_NODES * 8 * 4);
  float* aggS    = (float*)alloc((size_t)N_NODES * 8 * 4);
  float* UV      = (float*)alloc((size_t)16 * 512 * 4);

  // ---- enable 128KB dynamic LDS for the GEMM instantiations (host-side, capture-safe) ----
  const int GEMM_LDS = 131072;
  hipFuncSetAttribute(reinterpret_cast<const void*>(&gemm256_kernel<512,  false, false>),
                      hipFuncAttributeMaxDynamicSharedMemorySize, GEMM_LDS);
  hipFuncSetAttribute(reinterpret_cast<const void*>(&gemm256_kernel<1024, true,  true>),
                      hipFuncAttributeMaxDynamicSharedMemorySize, GEMM_LDS);
  hipFuncSetAttribute(reinterpret_cast<const void*>(&gemm256_kernel<512,  false, true>),
                      hipFuncAttributeMaxDynamicSharedMemorySize, GEMM_LDS);

  // ---- weight prep ----
  transpose_kernel<<<dim3(16, 16), 256, 0, stream>>>(pre_w, preT, 512, 512);
  transpose_kernel<<<dim3(16, 32), 256, 0, stream>>>(w1_0, w1T0, 1024, 512);
  transpose_kernel<<<dim3(16, 16), 256, 0, stream>>>(w2_0, w2T0, 512, 512);
  transpose_kernel<<<dim3(16, 16), 256, 0, stream>>>(w2_1, w2T1, 512, 512);
  uv_kernel<<<16, 512, 0, stream>>>(mem_0, w1_1, UV);   // rank-8 collapse tables for layer 1

  // ---- input cast ----
  castx_kernel<<<25024, 256, 0, stream>>>(x, xb);

  // ---- CSR build (per call; deterministic work) ----
  hipMemsetAsync(deg, 0, (size_t)N_NODES * 4, stream);
  degree_kernel<<<3125, 256, 0, stream>>>(dst, deg);
  scan1_kernel<<<98, 256, 0, stream>>>(deg, rowstart, bsum, N_NODES);
  scan2_kernel<<<1, 64, 0, stream>>>(bsum, 98);
  scan3_kernel<<<392, 256, 0, stream>>>(rowstart, bsum, cursor, N_NODES);
  scatter_kernel<<<3125, 256, 0, stream>>>(src, dst, cursor, csr);

  // pooling accumulators: gmax||gsum are contiguous -> one memset
  hipMemsetAsync(gmax, 0, (size_t)N_GRAPH * 1024 * 4 * 2, stream);
  ranges_kernel<<<2, 256, 0, stream>>>(batch, gstart);

  const int GG = 782;   // 391 M-tiles x 2 N-tiles

  // ---- pre conv: h = x @ pre_w + pre_b ----
  gemm256_kernel<512, false, false><<<GG, 512, GEMM_LDS, stream>>>(xb, nullptr, preT, pre_b, hb);

  // ---- layer 0 ----
  aggregate_kernel<<<25000, 256, 0, stream>>>(hb, rowstart, csr, aggb);
  gemm256_kernel<1024, true, true><<<GG, 512, GEMM_LDS, stream>>>(hb, aggb, w1T0, b1_0, y1b);
  gemm256_kernel<512, false, true><<<GG, 512, GEMM_LDS, stream>>>(y1b, nullptr, w2T0, b2_0, hb);
  memmod_pool_sim_kernel<<<782, 256, 0, stream>>>(hb, mem_0, batch, gmax, gsum, sim0);

  // ---- layer 1 (rank-8 collapsed front half) ----
  aggsim_kernel<<<391, 256, 0, stream>>>(sim0, rowstart, csr, aggS);
  z1y_kernel<<<25000, 256, 0, stream>>>(sim0, aggS, UV, b1_1, y1b);
  gemm256_kernel<512, false, true><<<GG, 512, GEMM_LDS, stream>>>(y1b, nullptr, w2T1, b2_1, hb);
  memmod_pool_kernel<<<782, 256, 0, stream>>>(hb, mem_1, batch, gmax, gsum, 512);

  // ---- readout ----
  pool2_kernel<<<N_GRAPH, 256, 0, stream>>>(gmax, gsum, gstart, gf);
  classify_kernel<<<N_GRAPH, 64, 0, stream>>>(gf, lin_w, lin_b, out);
}